// Round 1
// baseline (697.672 us; speedup 1.0000x reference)
//
#include <hip/hip_runtime.h>

#define N_NODES 50000
#define N_EDGES 1600000
#define EPLUS   1650000   // edges + self loops
#define HCH 128           // hidden channels (H*C)
#define NB 512            // graphs
#define NCLS 4
#define NBLK_SCAN 49      // ceil(50000/1024)

__device__ __forceinline__ float lrelu(float v) { return v > 0.f ? v : 0.2f * v; }

__global__ void k_zero_i32(int* p, int n) {
  int i = blockIdx.x * 256 + threadIdx.x;
  if (i < n) p[i] = 0;
}

__global__ void k_deg(const int* __restrict__ ei, int* __restrict__ deg) {
  int e = blockIdx.x * 256 + threadIdx.x;
  if (e >= EPLUS) return;
  int dst = (e < N_EDGES) ? ei[N_EDGES + e] : (e - N_EDGES);
  atomicAdd(&deg[dst], 1);
}

__global__ __launch_bounds__(256) void k_scan1(const int* __restrict__ deg,
                                               int* __restrict__ rowstart,
                                               int* __restrict__ bsum) {
  __shared__ int sm[256];
  int t = threadIdx.x;
  int base = blockIdx.x * 1024 + t * 4;
  int v0 = 0, v1 = 0, v2 = 0, v3 = 0;
  if (base + 0 < N_NODES) v0 = deg[base + 0];
  if (base + 1 < N_NODES) v1 = deg[base + 1];
  if (base + 2 < N_NODES) v2 = deg[base + 2];
  if (base + 3 < N_NODES) v3 = deg[base + 3];
  int s = v0 + v1 + v2 + v3;
  sm[t] = s;
  __syncthreads();
  for (int off = 1; off < 256; off <<= 1) {
    int xv = (t >= off) ? sm[t - off] : 0;
    __syncthreads();
    sm[t] += xv;
    __syncthreads();
  }
  int excl = sm[t] - s;
  if (t == 255) bsum[blockIdx.x] = sm[255];
  int run = excl;
  if (base + 0 < N_NODES) { rowstart[base + 0] = run; run += v0; }
  if (base + 1 < N_NODES) { rowstart[base + 1] = run; run += v1; }
  if (base + 2 < N_NODES) { rowstart[base + 2] = run; run += v2; }
  if (base + 3 < N_NODES) { rowstart[base + 3] = run; run += v3; }
}

__global__ void k_scan2(int* bsum, int nblk) {
  if (threadIdx.x == 0 && blockIdx.x == 0) {
    int acc = 0;
    for (int i = 0; i < nblk; ++i) { int v = bsum[i]; bsum[i] = acc; acc += v; }
  }
}

__global__ void k_scan3(int* __restrict__ rowstart, const int* __restrict__ bsum) {
  int i = blockIdx.x * 256 + threadIdx.x;
  if (i < N_NODES) rowstart[i] += bsum[i >> 10];
  else if (i == N_NODES) rowstart[N_NODES] = EPLUS;
}

__global__ void k_fill(const int* __restrict__ ei, const int* __restrict__ rowstart,
                       int* __restrict__ cursor, int* __restrict__ col) {
  int e = blockIdx.x * 256 + threadIdx.x;
  if (e >= EPLUS) return;
  int src, dst;
  if (e < N_EDGES) { src = ei[e]; dst = ei[N_EDGES + e]; }
  else { src = dst = e - N_EDGES; }
  int pos = rowstart[dst] + atomicAdd(&cursor[dst], 1);
  col[pos] = src;
}

// Y[N,128] = X[N,128] @ W[128,128]  (fp32, vector ALU)
__global__ __launch_bounds__(256) void k_gemm(const float* __restrict__ X,
                                              const float* __restrict__ W,
                                              float* __restrict__ Y) {
  __shared__ float As[128][36];   // stride 36: tm-groups land on distinct banks
  __shared__ float Bs[32][132];
  int tid = threadIdx.x;
  int r0 = blockIdx.x * 128;
  int tm = tid >> 4;   // 0..15 -> rows tm + 16*i
  int tn = tid & 15;   // 0..15 -> cols tn*8 .. +7
  float acc[8][8];
  #pragma unroll
  for (int i = 0; i < 8; ++i)
    #pragma unroll
    for (int j = 0; j < 8; ++j) acc[i][j] = 0.f;

  for (int kc = 0; kc < 128; kc += 32) {
    #pragma unroll
    for (int i = 0; i < 4; ++i) {          // X tile 128x32
      int q = tid + 256 * i;
      int row = q >> 3;
      int kq = (q & 7) << 2;
      int gr = r0 + row;
      float4 v = make_float4(0.f, 0.f, 0.f, 0.f);
      if (gr < N_NODES) v = *(const float4*)&X[(size_t)gr * 128 + kc + kq];
      *(float4*)&As[row][kq] = v;
    }
    #pragma unroll
    for (int i = 0; i < 4; ++i) {          // W tile 32x128
      int q = tid + 256 * i;
      int kr = q >> 5;
      int nq = (q & 31) << 2;
      float4 v = *(const float4*)&W[(size_t)(kc + kr) * 128 + nq];
      *(float4*)&Bs[kr][nq] = v;
    }
    __syncthreads();
    #pragma unroll 8
    for (int k = 0; k < 32; ++k) {
      float a[8];
      #pragma unroll
      for (int i = 0; i < 8; ++i) a[i] = As[tm + 16 * i][k];
      float4 bq0 = *(const float4*)&Bs[k][tn * 8];
      float4 bq1 = *(const float4*)&Bs[k][tn * 8 + 4];
      float b[8] = {bq0.x, bq0.y, bq0.z, bq0.w, bq1.x, bq1.y, bq1.z, bq1.w};
      #pragma unroll
      for (int i = 0; i < 8; ++i)
        #pragma unroll
        for (int j = 0; j < 8; ++j)
          acc[i][j] = fmaf(a[i], b[j], acc[i][j]);
    }
    __syncthreads();
  }
  #pragma unroll
  for (int i = 0; i < 8; ++i) {
    int row = r0 + tm + 16 * i;
    if (row < N_NODES) {
      *(float4*)&Y[(size_t)row * 128 + tn * 8] =
          make_float4(acc[i][0], acc[i][1], acc[i][2], acc[i][3]);
      *(float4*)&Y[(size_t)row * 128 + tn * 8 + 4] =
          make_float4(acc[i][4], acc[i][5], acc[i][6], acc[i][7]);
    }
  }
}

// es[n,h] = sum_c h[n,h*32+c]*a_src[h,c] ; ed likewise
__global__ __launch_bounds__(256) void k_edot(const float* __restrict__ Hm,
                                              const float* __restrict__ asrc,
                                              const float* __restrict__ adst,
                                              float* __restrict__ es,
                                              float* __restrict__ ed) {
  int lane = threadIdx.x & 63;
  int n = blockIdx.x * 4 + (threadIdx.x >> 6);
  if (n >= N_NODES) return;
  float h0 = Hm[(size_t)n * 128 + lane];
  float h1 = Hm[(size_t)n * 128 + 64 + lane];
  float s0 = h0 * asrc[lane], s1 = h1 * asrc[64 + lane];
  float d0 = h0 * adst[lane], d1 = h1 * adst[64 + lane];
  #pragma unroll
  for (int off = 1; off < 32; off <<= 1) {
    s0 += __shfl_xor(s0, off); s1 += __shfl_xor(s1, off);
    d0 += __shfl_xor(d0, off); d1 += __shfl_xor(d1, off);
  }
  if (lane == 0)  { es[n*4+0] = s0; es[n*4+2] = s1; ed[n*4+0] = d0; ed[n*4+2] = d1; }
  if (lane == 32) { es[n*4+1] = s0; es[n*4+3] = s1; ed[n*4+1] = d0; ed[n*4+3] = d1; }
}

// one wave per destination node: softmax over in-edges + weighted aggregation
__global__ __launch_bounds__(256) void k_attn(const float* __restrict__ Hm,
                                              const float* __restrict__ es,
                                              const float* __restrict__ ed,
                                              const int* __restrict__ rowstart,
                                              const int* __restrict__ col,
                                              const float* __restrict__ bias,
                                              float* __restrict__ outp, int do_relu) {
  int lane = threadIdx.x & 63;
  int n = blockIdx.x * 4 + (threadIdx.x >> 6);
  if (n >= N_NODES) return;
  int s0i = rowstart[n], s1i = rowstart[n + 1];
  float4 edv = *(const float4*)&ed[n * 4];

  // phase 1: per-head max over in-edges
  float m0 = -1e30f, m1 = -1e30f, m2 = -1e30f, m3 = -1e30f;
  for (int e = s0i + lane; e < s1i; e += 64) {
    int sc = col[e];
    float4 ev = *(const float4*)&es[sc * 4];
    m0 = fmaxf(m0, lrelu(ev.x + edv.x));
    m1 = fmaxf(m1, lrelu(ev.y + edv.y));
    m2 = fmaxf(m2, lrelu(ev.z + edv.z));
    m3 = fmaxf(m3, lrelu(ev.w + edv.w));
  }
  #pragma unroll
  for (int off = 1; off < 64; off <<= 1) {
    m0 = fmaxf(m0, __shfl_xor(m0, off));
    m1 = fmaxf(m1, __shfl_xor(m1, off));
    m2 = fmaxf(m2, __shfl_xor(m2, off));
    m3 = fmaxf(m3, __shfl_xor(m3, off));
  }
  // phase 1b: denominators
  float d0 = 0.f, d1 = 0.f, d2 = 0.f, d3 = 0.f;
  for (int e = s0i + lane; e < s1i; e += 64) {
    int sc = col[e];
    float4 ev = *(const float4*)&es[sc * 4];
    d0 += __expf(lrelu(ev.x + edv.x) - m0);
    d1 += __expf(lrelu(ev.y + edv.y) - m1);
    d2 += __expf(lrelu(ev.z + edv.z) - m2);
    d3 += __expf(lrelu(ev.w + edv.w) - m3);
  }
  #pragma unroll
  for (int off = 1; off < 64; off <<= 1) {
    d0 += __shfl_xor(d0, off); d1 += __shfl_xor(d1, off);
    d2 += __shfl_xor(d2, off); d3 += __shfl_xor(d3, off);
  }

  // phase 2: lanes own channels (2 each), serial over edges
  int c0 = lane * 2;
  int hh = lane >> 4;  // head of both channels
  float mh  = (hh & 2) ? ((hh & 1) ? m3 : m2) : ((hh & 1) ? m1 : m0);
  float dh  = (hh & 2) ? ((hh & 1) ? d3 : d2) : ((hh & 1) ? d1 : d0);
  float edh = (hh & 2) ? ((hh & 1) ? edv.w : edv.z) : ((hh & 1) ? edv.y : edv.x);
  float inv = 1.0f / (dh + 1e-16f);
  float a0 = 0.f, a1 = 0.f;
  for (int e = s0i; e < s1i; ++e) {
    int sc = col[e];
    float evh = es[sc * 4 + hh];
    float al = __expf(lrelu(evh + edh) - mh) * inv;
    float2 hv = *(const float2*)&Hm[(size_t)sc * 128 + c0];
    a0 = fmaf(al, hv.x, a0);
    a1 = fmaf(al, hv.y, a1);
  }
  float o0 = a0 + bias[c0];
  float o1 = a1 + bias[c0 + 1];
  if (do_relu) { o0 = fmaxf(o0, 0.f); o1 = fmaxf(o1, 0.f); }
  *(float2*)&outp[(size_t)n * 128 + c0] = make_float2(o0, o1);
}

// one block per graph: mean-pool (binary search on sorted batch) + 128->4 classifier
__global__ __launch_bounds__(128) void k_poolcls(const float* __restrict__ out2,
                                                 const int* __restrict__ batch,
                                                 const float* __restrict__ wc,
                                                 const float* __restrict__ bc,
                                                 float* __restrict__ y) {
  int b = blockIdx.x;
  int c = threadIdx.x;
  // lower_bound(batch, key)
  int lo = 0, hi = N_NODES;
  while (lo < hi) { int mid = (lo + hi) >> 1; if (batch[mid] < b) lo = mid + 1; else hi = mid; }
  int s = lo;
  lo = s; hi = N_NODES;
  while (lo < hi) { int mid = (lo + hi) >> 1; if (batch[mid] < b + 1) lo = mid + 1; else hi = mid; }
  int e = lo;
  float acc = 0.f;
  for (int nidx = s; nidx < e; ++nidx) acc += out2[(size_t)nidx * 128 + c];
  float cnt = (float)(e - s);
  float pooled = acc / fmaxf(cnt, 1.0f);
  float4 wrow = *(const float4*)&wc[c * 4];
  float wj[4] = {wrow.x, wrow.y, wrow.z, wrow.w};
  __shared__ float red[128];
  #pragma unroll
  for (int j = 0; j < 4; ++j) {
    red[c] = pooled * wj[j];
    __syncthreads();
    for (int off = 64; off > 0; off >>= 1) {
      if (c < off) red[c] += red[c + off];
      __syncthreads();
    }
    if (c == 0) y[b * 4 + j] = red[0] + bc[j];
    __syncthreads();
  }
}

extern "C" void kernel_launch(void* const* d_in, const int* in_sizes, int n_in,
                              void* d_out, int out_size, void* d_ws, size_t ws_size,
                              hipStream_t stream) {
  const float* x    = (const float*)d_in[0];
  const int*   ei   = (const int*)d_in[1];
  const int*   batch= (const int*)d_in[2];
  const float* w1   = (const float*)d_in[3];
  const float* as1  = (const float*)d_in[4];
  const float* ad1  = (const float*)d_in[5];
  const float* b1   = (const float*)d_in[6];
  const float* w2   = (const float*)d_in[7];
  const float* as2  = (const float*)d_in[8];
  const float* ad2  = (const float*)d_in[9];
  const float* b2   = (const float*)d_in[10];
  const float* bc   = (const float*)d_in[12];
  const float* wc   = (const float*)d_in[11];
  float* y = (float*)d_out;

  char* ws = (char*)d_ws;
  size_t o = 0;
  auto take = [&](size_t bytes) { void* p = ws + o; o = (o + bytes + 255) & ~(size_t)255; return p; };
  float* hbuf     = (float*)take((size_t)N_NODES * HCH * 4);  // h1 then h2
  float* obuf     = (float*)take((size_t)N_NODES * HCH * 4);  // out1 then out2
  float* es       = (float*)take((size_t)N_NODES * 4 * 4);
  float* ed       = (float*)take((size_t)N_NODES * 4 * 4);
  int*   deg      = (int*)take((size_t)N_NODES * 4);
  int*   cursor   = (int*)take((size_t)N_NODES * 4);
  int*   rowstart = (int*)take((size_t)(N_NODES + 1) * 4);
  int*   col      = (int*)take((size_t)EPLUS * 4);
  int*   bsum     = (int*)take(64 * 4);

  const int GE = (EPLUS + 255) / 256;           // 6446
  const int GN = (N_NODES + 255) / 256;         // 196
  const int GN1 = (N_NODES + 1 + 255) / 256;    // 196
  const int GW = N_NODES / 4;                   // 12500 (wave-per-node kernels)
  const int GG = (N_NODES + 127) / 128;         // 391 (gemm)

  // ---- CSR build (per launch; ws is not preserved between calls) ----
  k_zero_i32<<<GN, 256, 0, stream>>>(deg, N_NODES);
  k_zero_i32<<<GN, 256, 0, stream>>>(cursor, N_NODES);
  k_deg<<<GE, 256, 0, stream>>>(ei, deg);
  k_scan1<<<NBLK_SCAN, 256, 0, stream>>>(deg, rowstart, bsum);
  k_scan2<<<1, 64, 0, stream>>>(bsum, NBLK_SCAN);
  k_scan3<<<GN1, 256, 0, stream>>>(rowstart, bsum);
  k_fill<<<GE, 256, 0, stream>>>(ei, rowstart, cursor, col);

  // ---- layer 1 ----
  k_gemm<<<GG, 256, 0, stream>>>(x, w1, hbuf);
  k_edot<<<GW, 256, 0, stream>>>(hbuf, as1, ad1, es, ed);
  k_attn<<<GW, 256, 0, stream>>>(hbuf, es, ed, rowstart, col, b1, obuf, 1);

  // ---- layer 2 ----
  k_gemm<<<GG, 256, 0, stream>>>(obuf, w2, hbuf);
  k_edot<<<GW, 256, 0, stream>>>(hbuf, as2, ad2, es, ed);
  k_attn<<<GW, 256, 0, stream>>>(hbuf, es, ed, rowstart, col, b2, obuf, 0);

  // ---- pool + classifier ----
  k_poolcls<<<NB, 128, 0, stream>>>(obuf, batch, wc, bc, y);
}

// Round 2
// 421.183 us; speedup vs baseline: 1.6565x; 1.6565x over previous
//
#include <hip/hip_runtime.h>

#define N_NODES 50000
#define N_EDGES 1600000
#define EPLUS   1650000   // edges + self loops
#define HCH 128           // hidden channels (H*C)
#define NB 512            // graphs
#define NCLS 4
#define NBLK_SCAN 49      // ceil(50000/1024)

typedef unsigned int uint;

__device__ __forceinline__ float lrelu(float v) { return v > 0.f ? v : 0.2f * v; }
__device__ __forceinline__ float bf_lo(uint u) { return __uint_as_float(u << 16); }
__device__ __forceinline__ float bf_hi(uint u) { return __uint_as_float(u & 0xffff0000u); }

__global__ void k_zero_i32(int* p, int n) {
  int i = blockIdx.x * 256 + threadIdx.x;
  if (i < n) p[i] = 0;
}

__global__ void k_deg(const int* __restrict__ ei, int* __restrict__ deg) {
  int e = blockIdx.x * 256 + threadIdx.x;
  if (e >= EPLUS) return;
  int dst = (e < N_EDGES) ? ei[N_EDGES + e] : (e - N_EDGES);
  atomicAdd(&deg[dst], 1);
}

__global__ __launch_bounds__(256) void k_scan1(const int* __restrict__ deg,
                                               int* __restrict__ rowstart,
                                               int* __restrict__ bsum) {
  __shared__ int sm[256];
  int t = threadIdx.x;
  int base = blockIdx.x * 1024 + t * 4;
  int v0 = 0, v1 = 0, v2 = 0, v3 = 0;
  if (base + 0 < N_NODES) v0 = deg[base + 0];
  if (base + 1 < N_NODES) v1 = deg[base + 1];
  if (base + 2 < N_NODES) v2 = deg[base + 2];
  if (base + 3 < N_NODES) v3 = deg[base + 3];
  int s = v0 + v1 + v2 + v3;
  sm[t] = s;
  __syncthreads();
  for (int off = 1; off < 256; off <<= 1) {
    int xv = (t >= off) ? sm[t - off] : 0;
    __syncthreads();
    sm[t] += xv;
    __syncthreads();
  }
  int excl = sm[t] - s;
  if (t == 255) bsum[blockIdx.x] = sm[255];
  int run = excl;
  if (base + 0 < N_NODES) { rowstart[base + 0] = run; run += v0; }
  if (base + 1 < N_NODES) { rowstart[base + 1] = run; run += v1; }
  if (base + 2 < N_NODES) { rowstart[base + 2] = run; run += v2; }
  if (base + 3 < N_NODES) { rowstart[base + 3] = run; run += v3; }
}

__global__ void k_scan2(int* bsum, int nblk) {
  if (threadIdx.x == 0 && blockIdx.x == 0) {
    int acc = 0;
    for (int i = 0; i < nblk; ++i) { int v = bsum[i]; bsum[i] = acc; acc += v; }
  }
}

__global__ void k_scan3(int* __restrict__ rowstart, const int* __restrict__ bsum) {
  int i = blockIdx.x * 256 + threadIdx.x;
  if (i < N_NODES) rowstart[i] += bsum[i >> 10];
  else if (i == N_NODES) rowstart[N_NODES] = EPLUS;
}

__global__ void k_fill(const int* __restrict__ ei, const int* __restrict__ rowstart,
                       int* __restrict__ cursor, int* __restrict__ col) {
  int e = blockIdx.x * 256 + threadIdx.x;
  if (e >= EPLUS) return;
  int src, dst;
  if (e < N_EDGES) { src = ei[e]; dst = ei[N_EDGES + e]; }
  else { src = dst = e - N_EDGES; }
  int pos = rowstart[dst] + atomicAdd(&cursor[dst], 1);
  col[pos] = src;
}

// Y = X[N,128] @ W[128,128] (fp32 vector ALU). Epilogue: bf16-pack h into hbu,
// and compute es/ed (per-head dots with a_src/a_dst) from the fp32 accumulators.
__global__ __launch_bounds__(256) void k_gemm_fused(const float* __restrict__ X,
                                                    const float* __restrict__ W,
                                                    const float* __restrict__ asrc,
                                                    const float* __restrict__ adst,
                                                    uint* __restrict__ hbu,
                                                    float* __restrict__ es,
                                                    float* __restrict__ ed) {
  __shared__ float As[128][36];
  __shared__ float Bs[32][132];
  int tid = threadIdx.x;
  int r0 = blockIdx.x * 128;
  int tm = tid >> 4;   // 0..15 -> rows tm + 16*i
  int tn = tid & 15;   // 0..15 -> cols tn*8 .. +7  (all within head tn>>2)
  float acc[8][8];
  #pragma unroll
  for (int i = 0; i < 8; ++i)
    #pragma unroll
    for (int j = 0; j < 8; ++j) acc[i][j] = 0.f;

  for (int kc = 0; kc < 128; kc += 32) {
    #pragma unroll
    for (int i = 0; i < 4; ++i) {          // X tile 128x32
      int q = tid + 256 * i;
      int row = q >> 3;
      int kq = (q & 7) << 2;
      int gr = r0 + row;
      float4 v = make_float4(0.f, 0.f, 0.f, 0.f);
      if (gr < N_NODES) v = *(const float4*)&X[(size_t)gr * 128 + kc + kq];
      *(float4*)&As[row][kq] = v;
    }
    #pragma unroll
    for (int i = 0; i < 4; ++i) {          // W tile 32x128
      int q = tid + 256 * i;
      int kr = q >> 5;
      int nq = (q & 31) << 2;
      float4 v = *(const float4*)&W[(size_t)(kc + kr) * 128 + nq];
      *(float4*)&Bs[kr][nq] = v;
    }
    __syncthreads();
    #pragma unroll 8
    for (int k = 0; k < 32; ++k) {
      float a[8];
      #pragma unroll
      for (int i = 0; i < 8; ++i) a[i] = As[tm + 16 * i][k];
      float4 bq0 = *(const float4*)&Bs[k][tn * 8];
      float4 bq1 = *(const float4*)&Bs[k][tn * 8 + 4];
      float b[8] = {bq0.x, bq0.y, bq0.z, bq0.w, bq1.x, bq1.y, bq1.z, bq1.w};
      #pragma unroll
      for (int i = 0; i < 8; ++i)
        #pragma unroll
        for (int j = 0; j < 8; ++j)
          acc[i][j] = fmaf(a[i], b[j], acc[i][j]);
    }
    __syncthreads();
  }

  // epilogue: bf16 pack + per-head attention dots (exact fp32)
  float av_s[8], av_d[8];
  #pragma unroll
  for (int j = 0; j < 8; ++j) { av_s[j] = asrc[tn * 8 + j]; av_d[j] = adst[tn * 8 + j]; }
  int head = tn >> 2;
  #pragma unroll
  for (int i = 0; i < 8; ++i) {
    int row = r0 + tm + 16 * i;
    float ps = 0.f, pd = 0.f;
    uint us[8];
    #pragma unroll
    for (int j = 0; j < 8; ++j) {
      float v = acc[i][j];
      ps = fmaf(v, av_s[j], ps);
      pd = fmaf(v, av_d[j], pd);
      uint b = __float_as_uint(v);
      us[j] = (b + 0x7fffu + ((b >> 16) & 1u)) >> 16;   // RNE to bf16
    }
    // reduce over the 4 threads (same tm, same head): lanes base-aligned to 4
    ps += __shfl_xor(ps, 1); ps += __shfl_xor(ps, 2);
    pd += __shfl_xor(pd, 1); pd += __shfl_xor(pd, 2);
    if (row < N_NODES) {
      uint4 p;
      p.x = us[0] | (us[1] << 16);
      p.y = us[2] | (us[3] << 16);
      p.z = us[4] | (us[5] << 16);
      p.w = us[6] | (us[7] << 16);
      *(uint4*)&hbu[(size_t)row * 64 + tn * 4] = p;
      if ((tn & 3) == 0) {
        es[row * 4 + head] = ps;
        ed[row * 4 + head] = pd;
      }
    }
  }
}

// one wave per destination node, SINGLE pass: unnormalized exp weights,
// fused denominator, bf16 h gather, normalize at the end.
__global__ __launch_bounds__(256) void k_attn(const uint* __restrict__ hb,
                                              const float* __restrict__ es,
                                              const float* __restrict__ ed,
                                              const int* __restrict__ rowstart,
                                              const int* __restrict__ col,
                                              const float* __restrict__ bias,
                                              float* __restrict__ outp, int do_relu) {
  int lane = threadIdx.x & 63;
  int n = blockIdx.x * 4 + (threadIdx.x >> 6);
  if (n >= N_NODES) return;
  int s = rowstart[n], t = rowstart[n + 1];
  int hh = lane >> 4;          // head of this lane's 2 channels
  int c0 = lane * 2;
  float edh = ed[n * 4 + hh];
  float den = 0.f, a0 = 0.f, a1 = 0.f;

  int e = s;
  for (; e + 4 <= t; e += 4) {
    int sc0 = col[e], sc1 = col[e + 1], sc2 = col[e + 2], sc3 = col[e + 3];
    float ev0 = es[sc0 * 4 + hh], ev1 = es[sc1 * 4 + hh];
    float ev2 = es[sc2 * 4 + hh], ev3 = es[sc3 * 4 + hh];
    uint u0 = hb[(size_t)sc0 * 64 + lane], u1 = hb[(size_t)sc1 * 64 + lane];
    uint u2 = hb[(size_t)sc2 * 64 + lane], u3 = hb[(size_t)sc3 * 64 + lane];
    float w0 = __expf(lrelu(ev0 + edh));
    float w1 = __expf(lrelu(ev1 + edh));
    float w2 = __expf(lrelu(ev2 + edh));
    float w3 = __expf(lrelu(ev3 + edh));
    den += (w0 + w1) + (w2 + w3);
    a0 = fmaf(w0, bf_lo(u0), a0); a1 = fmaf(w0, bf_hi(u0), a1);
    a0 = fmaf(w1, bf_lo(u1), a0); a1 = fmaf(w1, bf_hi(u1), a1);
    a0 = fmaf(w2, bf_lo(u2), a0); a1 = fmaf(w2, bf_hi(u2), a1);
    a0 = fmaf(w3, bf_lo(u3), a0); a1 = fmaf(w3, bf_hi(u3), a1);
  }
  for (; e < t; ++e) {
    int sc = col[e];
    float ev = es[sc * 4 + hh];
    uint u = hb[(size_t)sc * 64 + lane];
    float w = __expf(lrelu(ev + edh));
    den += w;
    a0 = fmaf(w, bf_lo(u), a0);
    a1 = fmaf(w, bf_hi(u), a1);
  }
  float inv = 1.0f / (den + 1e-16f);
  float o0 = a0 * inv + bias[c0];
  float o1 = a1 * inv + bias[c0 + 1];
  if (do_relu) { o0 = fmaxf(o0, 0.f); o1 = fmaxf(o1, 0.f); }
  *(float2*)&outp[(size_t)n * 128 + c0] = make_float2(o0, o1);
}

// one block per graph: mean-pool (binary search on sorted batch) + 128->4 classifier
__global__ __launch_bounds__(128) void k_poolcls(const float* __restrict__ out2,
                                                 const int* __restrict__ batch,
                                                 const float* __restrict__ wc,
                                                 const float* __restrict__ bc,
                                                 float* __restrict__ y) {
  int b = blockIdx.x;
  int c = threadIdx.x;
  int lo = 0, hi = N_NODES;
  while (lo < hi) { int mid = (lo + hi) >> 1; if (batch[mid] < b) lo = mid + 1; else hi = mid; }
  int s = lo;
  lo = s; hi = N_NODES;
  while (lo < hi) { int mid = (lo + hi) >> 1; if (batch[mid] < b + 1) lo = mid + 1; else hi = mid; }
  int e = lo;
  float acc0 = 0.f, acc1 = 0.f;
  int nidx = s;
  for (; nidx + 2 <= e; nidx += 2) {
    acc0 += out2[(size_t)nidx * 128 + c];
    acc1 += out2[(size_t)(nidx + 1) * 128 + c];
  }
  if (nidx < e) acc0 += out2[(size_t)nidx * 128 + c];
  float acc = acc0 + acc1;
  float cnt = (float)(e - s);
  float pooled = acc / fmaxf(cnt, 1.0f);
  float4 wrow = *(const float4*)&wc[c * 4];
  float wj[4] = {wrow.x, wrow.y, wrow.z, wrow.w};
  __shared__ float red[128];
  #pragma unroll
  for (int j = 0; j < 4; ++j) {
    red[c] = pooled * wj[j];
    __syncthreads();
    for (int off = 64; off > 0; off >>= 1) {
      if (c < off) red[c] += red[c + off];
      __syncthreads();
    }
    if (c == 0) y[b * 4 + j] = red[0] + bc[j];
    __syncthreads();
  }
}

extern "C" void kernel_launch(void* const* d_in, const int* in_sizes, int n_in,
                              void* d_out, int out_size, void* d_ws, size_t ws_size,
                              hipStream_t stream) {
  const float* x    = (const float*)d_in[0];
  const int*   ei   = (const int*)d_in[1];
  const int*   batch= (const int*)d_in[2];
  const float* w1   = (const float*)d_in[3];
  const float* as1  = (const float*)d_in[4];
  const float* ad1  = (const float*)d_in[5];
  const float* b1   = (const float*)d_in[6];
  const float* w2   = (const float*)d_in[7];
  const float* as2  = (const float*)d_in[8];
  const float* ad2  = (const float*)d_in[9];
  const float* b2   = (const float*)d_in[10];
  const float* wc   = (const float*)d_in[11];
  const float* bc   = (const float*)d_in[12];
  float* y = (float*)d_out;

  char* ws = (char*)d_ws;
  size_t o = 0;
  auto take = [&](size_t bytes) { void* p = ws + o; o = (o + bytes + 255) & ~(size_t)255; return p; };
  uint*  hbu      = (uint*)take((size_t)N_NODES * 64 * 4);     // bf16 h, packed 2/word
  float* obuf     = (float*)take((size_t)N_NODES * HCH * 4);   // fp32 layer outputs
  float* es       = (float*)take((size_t)N_NODES * 4 * 4);
  float* ed       = (float*)take((size_t)N_NODES * 4 * 4);
  int*   degcur   = (int*)take((size_t)2 * N_NODES * 4);       // deg | cursor
  int*   rowstart = (int*)take((size_t)(N_NODES + 1) * 4);
  int*   col      = (int*)take((size_t)EPLUS * 4);
  int*   bsum     = (int*)take(64 * 4);
  int* deg = degcur;
  int* cursor = degcur + N_NODES;

  const int GE  = (EPLUS + 255) / 256;
  const int GN2 = (2 * N_NODES + 255) / 256;
  const int GN1 = (N_NODES + 1 + 255) / 256;
  const int GW  = N_NODES / 4;               // 12500 wave-per-node
  const int GG  = (N_NODES + 127) / 128;     // 391 gemm blocks

  // ---- CSR build ----
  k_zero_i32<<<GN2, 256, 0, stream>>>(degcur, 2 * N_NODES);
  k_deg<<<GE, 256, 0, stream>>>(ei, deg);
  k_scan1<<<NBLK_SCAN, 256, 0, stream>>>(deg, rowstart, bsum);
  k_scan2<<<1, 64, 0, stream>>>(bsum, NBLK_SCAN);
  k_scan3<<<GN1, 256, 0, stream>>>(rowstart, bsum);
  k_fill<<<GE, 256, 0, stream>>>(ei, rowstart, cursor, col);

  // ---- layer 1 ----
  k_gemm_fused<<<GG, 256, 0, stream>>>(x, w1, as1, ad1, hbu, es, ed);
  k_attn<<<GW, 256, 0, stream>>>(hbu, es, ed, rowstart, col, b1, obuf, 1);

  // ---- layer 2 ----
  k_gemm_fused<<<GG, 256, 0, stream>>>(obuf, w2, as2, ad2, hbu, es, ed);
  k_attn<<<GW, 256, 0, stream>>>(hbu, es, ed, rowstart, col, b2, obuf, 0);

  // ---- pool + classifier ----
  k_poolcls<<<NB, 128, 0, stream>>>(obuf, batch, wc, bc, y);
}

// Round 3
// 340.537 us; speedup vs baseline: 2.0487x; 1.2368x over previous
//
#include <hip/hip_runtime.h>

#define N_NODES 50000
#define N_EDGES 1600000
#define EPLUS   1650000   // edges + self loops
#define HCH 128           // hidden channels (H*C)
#define NB 512            // graphs
#define NCLS 4
#define NBLK_SCAN 49      // ceil(50000/1024)

typedef unsigned int uint;

__device__ __forceinline__ float lrelu(float v) { return v > 0.f ? v : 0.2f * v; }
__device__ __forceinline__ float bf_lo(uint u) { return __uint_as_float(u << 16); }
__device__ __forceinline__ float bf_hi(uint u) { return __uint_as_float(u & 0xffff0000u); }

__global__ void k_zero_i32(int* p, int n) {
  int i = blockIdx.x * 256 + threadIdx.x;
  if (i < n) p[i] = 0;
}

// degree + within-segment offset in ONE atomic pass; 4 independent atomics
// in flight per lane to hide the atomic-return latency.
__global__ void k_degoff(const int* __restrict__ ei, int* __restrict__ deg,
                         int* __restrict__ offs) {
  int i0 = blockIdx.x * 1024 + threadIdx.x;
  #pragma unroll
  for (int u = 0; u < 4; ++u) {
    int e = i0 + u * 256;
    if (e < EPLUS) {
      int dst = (e < N_EDGES) ? ei[N_EDGES + e] : (e - N_EDGES);
      offs[e] = atomicAdd(&deg[dst], 1);
    }
  }
}

__global__ __launch_bounds__(256) void k_scan1(const int* __restrict__ deg,
                                               int* __restrict__ rowstart,
                                               int* __restrict__ bsum) {
  __shared__ int sm[256];
  int t = threadIdx.x;
  int base = blockIdx.x * 1024 + t * 4;
  int v0 = 0, v1 = 0, v2 = 0, v3 = 0;
  if (base + 0 < N_NODES) v0 = deg[base + 0];
  if (base + 1 < N_NODES) v1 = deg[base + 1];
  if (base + 2 < N_NODES) v2 = deg[base + 2];
  if (base + 3 < N_NODES) v3 = deg[base + 3];
  int s = v0 + v1 + v2 + v3;
  sm[t] = s;
  __syncthreads();
  for (int off = 1; off < 256; off <<= 1) {
    int xv = (t >= off) ? sm[t - off] : 0;
    __syncthreads();
    sm[t] += xv;
    __syncthreads();
  }
  int excl = sm[t] - s;
  if (t == 255) bsum[blockIdx.x] = sm[255];
  int run = excl;
  if (base + 0 < N_NODES) { rowstart[base + 0] = run; run += v0; }
  if (base + 1 < N_NODES) { rowstart[base + 1] = run; run += v1; }
  if (base + 2 < N_NODES) { rowstart[base + 2] = run; run += v2; }
  if (base + 3 < N_NODES) { rowstart[base + 3] = run; run += v3; }
}

__global__ void k_scan2(int* bsum, int nblk) {
  if (threadIdx.x == 0 && blockIdx.x == 0) {
    int acc = 0;
    for (int i = 0; i < nblk; ++i) { int v = bsum[i]; bsum[i] = acc; acc += v; }
  }
}

__global__ void k_scan3(int* __restrict__ rowstart, const int* __restrict__ bsum) {
  int i = blockIdx.x * 256 + threadIdx.x;
  if (i < N_NODES) rowstart[i] += bsum[i >> 10];
  else if (i == N_NODES) rowstart[N_NODES] = EPLUS;
}

// no atomics: pos comes from rowstart + precomputed offs. Stores are
// fire-and-forget; pure streaming reads otherwise.
__global__ void k_fill2(const int* __restrict__ ei, const int* __restrict__ rowstart,
                        const int* __restrict__ offs, int* __restrict__ col) {
  int i0 = blockIdx.x * 1024 + threadIdx.x;
  #pragma unroll
  for (int u = 0; u < 4; ++u) {
    int e = i0 + u * 256;
    if (e < EPLUS) {
      int src, dst;
      if (e < N_EDGES) { src = ei[e]; dst = ei[N_EDGES + e]; }
      else { src = dst = e - N_EDGES; }
      col[rowstart[dst] + offs[e]] = src;
    }
  }
}

// Y = X[N,128] @ W[128,128] (fp32 vector ALU). Epilogue: bf16-pack h into hbu,
// and compute es/ed (per-head dots with a_src/a_dst) from the fp32 accumulators.
__global__ __launch_bounds__(256) void k_gemm_fused(const float* __restrict__ X,
                                                    const float* __restrict__ W,
                                                    const float* __restrict__ asrc,
                                                    const float* __restrict__ adst,
                                                    uint* __restrict__ hbu,
                                                    float* __restrict__ es,
                                                    float* __restrict__ ed) {
  __shared__ float As[128][36];
  __shared__ float Bs[32][132];
  int tid = threadIdx.x;
  int r0 = blockIdx.x * 128;
  int tm = tid >> 4;   // 0..15 -> rows tm + 16*i
  int tn = tid & 15;   // 0..15 -> cols tn*8 .. +7  (all within head tn>>2)
  float acc[8][8];
  #pragma unroll
  for (int i = 0; i < 8; ++i)
    #pragma unroll
    for (int j = 0; j < 8; ++j) acc[i][j] = 0.f;

  for (int kc = 0; kc < 128; kc += 32) {
    #pragma unroll
    for (int i = 0; i < 4; ++i) {          // X tile 128x32
      int q = tid + 256 * i;
      int row = q >> 3;
      int kq = (q & 7) << 2;
      int gr = r0 + row;
      float4 v = make_float4(0.f, 0.f, 0.f, 0.f);
      if (gr < N_NODES) v = *(const float4*)&X[(size_t)gr * 128 + kc + kq];
      *(float4*)&As[row][kq] = v;
    }
    #pragma unroll
    for (int i = 0; i < 4; ++i) {          // W tile 32x128
      int q = tid + 256 * i;
      int kr = q >> 5;
      int nq = (q & 31) << 2;
      float4 v = *(const float4*)&W[(size_t)(kc + kr) * 128 + nq];
      *(float4*)&Bs[kr][nq] = v;
    }
    __syncthreads();
    #pragma unroll 8
    for (int k = 0; k < 32; ++k) {
      float a[8];
      #pragma unroll
      for (int i = 0; i < 8; ++i) a[i] = As[tm + 16 * i][k];
      float4 bq0 = *(const float4*)&Bs[k][tn * 8];
      float4 bq1 = *(const float4*)&Bs[k][tn * 8 + 4];
      float b[8] = {bq0.x, bq0.y, bq0.z, bq0.w, bq1.x, bq1.y, bq1.z, bq1.w};
      #pragma unroll
      for (int i = 0; i < 8; ++i)
        #pragma unroll
        for (int j = 0; j < 8; ++j)
          acc[i][j] = fmaf(a[i], b[j], acc[i][j]);
    }
    __syncthreads();
  }

  // epilogue: bf16 pack + per-head attention dots (exact fp32)
  float av_s[8], av_d[8];
  #pragma unroll
  for (int j = 0; j < 8; ++j) { av_s[j] = asrc[tn * 8 + j]; av_d[j] = adst[tn * 8 + j]; }
  int head = tn >> 2;
  #pragma unroll
  for (int i = 0; i < 8; ++i) {
    int row = r0 + tm + 16 * i;
    float ps = 0.f, pd = 0.f;
    uint us[8];
    #pragma unroll
    for (int j = 0; j < 8; ++j) {
      float v = acc[i][j];
      ps = fmaf(v, av_s[j], ps);
      pd = fmaf(v, av_d[j], pd);
      uint b = __float_as_uint(v);
      us[j] = (b + 0x7fffu + ((b >> 16) & 1u)) >> 16;   // RNE to bf16
    }
    // reduce over the 4 threads (same tm, same head): lanes base-aligned to 4
    ps += __shfl_xor(ps, 1); ps += __shfl_xor(ps, 2);
    pd += __shfl_xor(pd, 1); pd += __shfl_xor(pd, 2);
    if (row < N_NODES) {
      uint4 p;
      p.x = us[0] | (us[1] << 16);
      p.y = us[2] | (us[3] << 16);
      p.z = us[4] | (us[5] << 16);
      p.w = us[6] | (us[7] << 16);
      *(uint4*)&hbu[(size_t)row * 64 + tn * 4] = p;
      if ((tn & 3) == 0) {
        es[row * 4 + head] = ps;
        ed[row * 4 + head] = pd;
      }
    }
  }
}

// one wave per destination node, SINGLE pass: unnormalized exp weights,
// fused denominator, bf16 h gather, normalize at the end. 8-deep unroll
// for 8 independent gather chains per lane.
__global__ __launch_bounds__(256) void k_attn(const uint* __restrict__ hb,
                                              const float* __restrict__ es,
                                              const float* __restrict__ ed,
                                              const int* __restrict__ rowstart,
                                              const int* __restrict__ col,
                                              const float* __restrict__ bias,
                                              float* __restrict__ outp, int do_relu) {
  int lane = threadIdx.x & 63;
  int n = blockIdx.x * 4 + (threadIdx.x >> 6);
  if (n >= N_NODES) return;
  int s = rowstart[n], t = rowstart[n + 1];
  int hh = lane >> 4;          // head of this lane's 2 channels
  int c0 = lane * 2;
  float edh = ed[n * 4 + hh];
  float den = 0.f, a0 = 0.f, a1 = 0.f;
  float den2 = 0.f, b0 = 0.f, b1 = 0.f;

  int e = s;
  for (; e + 8 <= t; e += 8) {
    int sc[8];
    #pragma unroll
    for (int u = 0; u < 8; ++u) sc[u] = col[e + u];
    float ev[8];
    uint hu[8];
    #pragma unroll
    for (int u = 0; u < 8; ++u) ev[u] = es[sc[u] * 4 + hh];
    #pragma unroll
    for (int u = 0; u < 8; ++u) hu[u] = hb[(size_t)sc[u] * 64 + lane];
    #pragma unroll
    for (int u = 0; u < 8; ++u) {
      float w = __expf(lrelu(ev[u] + edh));
      if (u & 1) {
        den2 += w; b0 = fmaf(w, bf_lo(hu[u]), b0); b1 = fmaf(w, bf_hi(hu[u]), b1);
      } else {
        den  += w; a0 = fmaf(w, bf_lo(hu[u]), a0); a1 = fmaf(w, bf_hi(hu[u]), a1);
      }
    }
  }
  for (; e < t; ++e) {
    int sc = col[e];
    float ev = es[sc * 4 + hh];
    uint u = hb[(size_t)sc * 64 + lane];
    float w = __expf(lrelu(ev + edh));
    den += w;
    a0 = fmaf(w, bf_lo(u), a0);
    a1 = fmaf(w, bf_hi(u), a1);
  }
  den += den2; a0 += b0; a1 += b1;
  float inv = 1.0f / (den + 1e-16f);
  float o0 = a0 * inv + bias[c0];
  float o1 = a1 * inv + bias[c0 + 1];
  if (do_relu) { o0 = fmaxf(o0, 0.f); o1 = fmaxf(o1, 0.f); }
  *(float2*)&outp[(size_t)n * 128 + c0] = make_float2(o0, o1);
}

// one block per graph: mean-pool (binary search on sorted batch) + 128->4 classifier
__global__ __launch_bounds__(128) void k_poolcls(const float* __restrict__ out2,
                                                 const int* __restrict__ batch,
                                                 const float* __restrict__ wc,
                                                 const float* __restrict__ bc,
                                                 float* __restrict__ y) {
  int b = blockIdx.x;
  int c = threadIdx.x;
  int lo = 0, hi = N_NODES;
  while (lo < hi) { int mid = (lo + hi) >> 1; if (batch[mid] < b) lo = mid + 1; else hi = mid; }
  int s = lo;
  lo = s; hi = N_NODES;
  while (lo < hi) { int mid = (lo + hi) >> 1; if (batch[mid] < b + 1) lo = mid + 1; else hi = mid; }
  int e = lo;
  float acc0 = 0.f, acc1 = 0.f, acc2 = 0.f, acc3 = 0.f;
  int nidx = s;
  for (; nidx + 4 <= e; nidx += 4) {
    acc0 += out2[(size_t)nidx * 128 + c];
    acc1 += out2[(size_t)(nidx + 1) * 128 + c];
    acc2 += out2[(size_t)(nidx + 2) * 128 + c];
    acc3 += out2[(size_t)(nidx + 3) * 128 + c];
  }
  for (; nidx < e; ++nidx) acc0 += out2[(size_t)nidx * 128 + c];
  float acc = (acc0 + acc1) + (acc2 + acc3);
  float cnt = (float)(e - s);
  float pooled = acc / fmaxf(cnt, 1.0f);
  float4 wrow = *(const float4*)&wc[c * 4];
  float wj[4] = {wrow.x, wrow.y, wrow.z, wrow.w};
  __shared__ float red[128];
  #pragma unroll
  for (int j = 0; j < 4; ++j) {
    red[c] = pooled * wj[j];
    __syncthreads();
    for (int off = 64; off > 0; off >>= 1) {
      if (c < off) red[c] += red[c + off];
      __syncthreads();
    }
    if (c == 0) y[b * 4 + j] = red[0] + bc[j];
    __syncthreads();
  }
}

extern "C" void kernel_launch(void* const* d_in, const int* in_sizes, int n_in,
                              void* d_out, int out_size, void* d_ws, size_t ws_size,
                              hipStream_t stream) {
  const float* x    = (const float*)d_in[0];
  const int*   ei   = (const int*)d_in[1];
  const int*   batch= (const int*)d_in[2];
  const float* w1   = (const float*)d_in[3];
  const float* as1  = (const float*)d_in[4];
  const float* ad1  = (const float*)d_in[5];
  const float* b1   = (const float*)d_in[6];
  const float* w2   = (const float*)d_in[7];
  const float* as2  = (const float*)d_in[8];
  const float* ad2  = (const float*)d_in[9];
  const float* b2   = (const float*)d_in[10];
  const float* wc   = (const float*)d_in[11];
  const float* bc   = (const float*)d_in[12];
  float* y = (float*)d_out;

  char* ws = (char*)d_ws;
  size_t o = 0;
  auto take = [&](size_t bytes) { void* p = ws + o; o = (o + bytes + 255) & ~(size_t)255; return p; };
  uint*  hbu      = (uint*)take((size_t)N_NODES * 64 * 4);     // bf16 h, packed 2/word
  float* obuf     = (float*)take((size_t)N_NODES * HCH * 4);   // fp32 layer outputs
  float* es       = (float*)take((size_t)N_NODES * 4 * 4);
  float* ed       = (float*)take((size_t)N_NODES * 4 * 4);
  int*   deg      = (int*)take((size_t)N_NODES * 4);
  int*   offs     = (int*)take((size_t)EPLUS * 4);
  int*   rowstart = (int*)take((size_t)(N_NODES + 1) * 4);
  int*   col      = (int*)take((size_t)EPLUS * 4);
  int*   bsum     = (int*)take(64 * 4);

  const int GE4 = (EPLUS + 1023) / 1024;     // 4 edges per thread
  const int GN  = (N_NODES + 255) / 256;
  const int GN1 = (N_NODES + 1 + 255) / 256;
  const int GW  = N_NODES / 4;               // 12500 wave-per-node
  const int GG  = (N_NODES + 127) / 128;     // 391 gemm blocks

  // ---- CSR build ----
  k_zero_i32<<<GN, 256, 0, stream>>>(deg, N_NODES);
  k_degoff<<<GE4, 256, 0, stream>>>(ei, deg, offs);
  k_scan1<<<NBLK_SCAN, 256, 0, stream>>>(deg, rowstart, bsum);
  k_scan2<<<1, 64, 0, stream>>>(bsum, NBLK_SCAN);
  k_scan3<<<GN1, 256, 0, stream>>>(rowstart, bsum);
  k_fill2<<<GE4, 256, 0, stream>>>(ei, rowstart, offs, col);

  // ---- layer 1 ----
  k_gemm_fused<<<GG, 256, 0, stream>>>(x, w1, as1, ad1, hbu, es, ed);
  k_attn<<<GW, 256, 0, stream>>>(hbu, es, ed, rowstart, col, b1, obuf, 1);

  // ---- layer 2 ----
  k_gemm_fused<<<GG, 256, 0, stream>>>(obuf, w2, as2, ad2, hbu, es, ed);
  k_attn<<<GW, 256, 0, stream>>>(hbu, es, ed, rowstart, col, b2, obuf, 0);

  // ---- pool + classifier ----
  k_poolcls<<<NB, 128, 0, stream>>>(obuf, batch, wc, bc, y);
}

// Round 4
// 321.784 us; speedup vs baseline: 2.1681x; 1.0583x over previous
//
#include <hip/hip_runtime.h>

#define N_NODES 50000
#define N_EDGES 1600000
#define EPLUS   1650000   // edges + self loops
#define HCH 128           // hidden channels (H*C)
#define NB 512            // graphs
#define NCLS 4
#define NBLK_SCAN 49      // ceil(50000/1024)

typedef unsigned int uint;

__device__ __forceinline__ float lrelu(float v) { return v > 0.f ? v : 0.2f * v; }
__device__ __forceinline__ float bf_lo(uint u) { return __uint_as_float(u << 16); }
__device__ __forceinline__ float bf_hi(uint u) { return __uint_as_float(u & 0xffff0000u); }

__global__ void k_zero_i32(int* p, int n) {
  int i = blockIdx.x * 256 + threadIdx.x;
  if (i < n) p[i] = 0;
}

// degree + within-segment offset in ONE atomic pass; 8 independent atomics
// in flight per lane to hide the atomic-return latency.
__global__ void k_degoff(const int* __restrict__ ei, int* __restrict__ deg,
                         int* __restrict__ offs) {
  int i0 = blockIdx.x * 2048 + threadIdx.x;
  #pragma unroll
  for (int u = 0; u < 8; ++u) {
    int e = i0 + u * 256;
    if (e < EPLUS) {
      int dst = (e < N_EDGES) ? ei[N_EDGES + e] : (e - N_EDGES);
      offs[e] = atomicAdd(&deg[dst], 1);
    }
  }
}

__global__ __launch_bounds__(256) void k_scan1(const int* __restrict__ deg,
                                               int* __restrict__ rowstart,
                                               int* __restrict__ bsum) {
  __shared__ int sm[256];
  int t = threadIdx.x;
  int base = blockIdx.x * 1024 + t * 4;
  int v0 = 0, v1 = 0, v2 = 0, v3 = 0;
  if (base + 0 < N_NODES) v0 = deg[base + 0];
  if (base + 1 < N_NODES) v1 = deg[base + 1];
  if (base + 2 < N_NODES) v2 = deg[base + 2];
  if (base + 3 < N_NODES) v3 = deg[base + 3];
  int s = v0 + v1 + v2 + v3;
  sm[t] = s;
  __syncthreads();
  for (int off = 1; off < 256; off <<= 1) {
    int xv = (t >= off) ? sm[t - off] : 0;
    __syncthreads();
    sm[t] += xv;
    __syncthreads();
  }
  int excl = sm[t] - s;
  if (t == 255) bsum[blockIdx.x] = sm[255];
  int run = excl;
  if (base + 0 < N_NODES) { rowstart[base + 0] = run; run += v0; }
  if (base + 1 < N_NODES) { rowstart[base + 1] = run; run += v1; }
  if (base + 2 < N_NODES) { rowstart[base + 2] = run; run += v2; }
  if (base + 3 < N_NODES) { rowstart[base + 3] = run; run += v3; }
}

__global__ void k_scan2(int* bsum, int nblk) {
  if (threadIdx.x == 0 && blockIdx.x == 0) {
    int acc = 0;
    for (int i = 0; i < nblk; ++i) { int v = bsum[i]; bsum[i] = acc; acc += v; }
  }
}

__global__ void k_scan3(int* __restrict__ rowstart, const int* __restrict__ bsum) {
  int i = blockIdx.x * 256 + threadIdx.x;
  if (i < N_NODES) rowstart[i] += bsum[i >> 10];
  else if (i == N_NODES) rowstart[N_NODES] = EPLUS;
}

// no atomics: pos comes from rowstart + precomputed offs. Stores are
// fire-and-forget; pure streaming reads otherwise.
__global__ void k_fill2(const int* __restrict__ ei, const int* __restrict__ rowstart,
                        const int* __restrict__ offs, int* __restrict__ col) {
  int i0 = blockIdx.x * 2048 + threadIdx.x;
  #pragma unroll
  for (int u = 0; u < 8; ++u) {
    int e = i0 + u * 256;
    if (e < EPLUS) {
      int src, dst;
      if (e < N_EDGES) { src = ei[e]; dst = ei[N_EDGES + e]; }
      else { src = dst = e - N_EDGES; }
      col[rowstart[dst] + offs[e]] = src;
    }
  }
}

// Y = X[N,128] @ W[128,128] (fp32 vector ALU). Epilogue: bf16-pack h into hbu,
// and compute es/ed (per-head dots with a_src/a_dst) from the fp32 accumulators.
__global__ __launch_bounds__(256) void k_gemm_fused(const float* __restrict__ X,
                                                    const float* __restrict__ W,
                                                    const float* __restrict__ asrc,
                                                    const float* __restrict__ adst,
                                                    uint* __restrict__ hbu,
                                                    float* __restrict__ es,
                                                    float* __restrict__ ed) {
  __shared__ float As[128][36];
  __shared__ float Bs[32][132];
  int tid = threadIdx.x;
  int r0 = blockIdx.x * 128;
  int tm = tid >> 4;   // 0..15 -> rows tm + 16*i
  int tn = tid & 15;   // 0..15 -> cols tn*8 .. +7  (all within head tn>>2)
  float acc[8][8];
  #pragma unroll
  for (int i = 0; i < 8; ++i)
    #pragma unroll
    for (int j = 0; j < 8; ++j) acc[i][j] = 0.f;

  for (int kc = 0; kc < 128; kc += 32) {
    #pragma unroll
    for (int i = 0; i < 4; ++i) {          // X tile 128x32
      int q = tid + 256 * i;
      int row = q >> 3;
      int kq = (q & 7) << 2;
      int gr = r0 + row;
      float4 v = make_float4(0.f, 0.f, 0.f, 0.f);
      if (gr < N_NODES) v = *(const float4*)&X[(size_t)gr * 128 + kc + kq];
      *(float4*)&As[row][kq] = v;
    }
    #pragma unroll
    for (int i = 0; i < 4; ++i) {          // W tile 32x128
      int q = tid + 256 * i;
      int kr = q >> 5;
      int nq = (q & 31) << 2;
      float4 v = *(const float4*)&W[(size_t)(kc + kr) * 128 + nq];
      *(float4*)&Bs[kr][nq] = v;
    }
    __syncthreads();
    #pragma unroll 8
    for (int k = 0; k < 32; ++k) {
      float a[8];
      #pragma unroll
      for (int i = 0; i < 8; ++i) a[i] = As[tm + 16 * i][k];
      float4 bq0 = *(const float4*)&Bs[k][tn * 8];
      float4 bq1 = *(const float4*)&Bs[k][tn * 8 + 4];
      float b[8] = {bq0.x, bq0.y, bq0.z, bq0.w, bq1.x, bq1.y, bq1.z, bq1.w};
      #pragma unroll
      for (int i = 0; i < 8; ++i)
        #pragma unroll
        for (int j = 0; j < 8; ++j)
          acc[i][j] = fmaf(a[i], b[j], acc[i][j]);
    }
    __syncthreads();
  }

  // epilogue: bf16 pack + per-head attention dots (exact fp32)
  float av_s[8], av_d[8];
  #pragma unroll
  for (int j = 0; j < 8; ++j) { av_s[j] = asrc[tn * 8 + j]; av_d[j] = adst[tn * 8 + j]; }
  int head = tn >> 2;
  #pragma unroll
  for (int i = 0; i < 8; ++i) {
    int row = r0 + tm + 16 * i;
    float ps = 0.f, pd = 0.f;
    uint us[8];
    #pragma unroll
    for (int j = 0; j < 8; ++j) {
      float v = acc[i][j];
      ps = fmaf(v, av_s[j], ps);
      pd = fmaf(v, av_d[j], pd);
      uint b = __float_as_uint(v);
      us[j] = (b + 0x7fffu + ((b >> 16) & 1u)) >> 16;   // RNE to bf16
    }
    // reduce over the 4 threads (same tm, same head): lanes base-aligned to 4
    ps += __shfl_xor(ps, 1); ps += __shfl_xor(ps, 2);
    pd += __shfl_xor(pd, 1); pd += __shfl_xor(pd, 2);
    if (row < N_NODES) {
      uint4 p;
      p.x = us[0] | (us[1] << 16);
      p.y = us[2] | (us[3] << 16);
      p.z = us[4] | (us[5] << 16);
      p.w = us[6] | (us[7] << 16);
      *(uint4*)&hbu[(size_t)row * 64 + tn * 4] = p;
      if ((tn & 3) == 0) {
        es[row * 4 + head] = ps;
        ed[row * 4 + head] = pd;
      }
    }
  }
}

// one wave per destination node. Two-phase via LDS:
//  A: lanes parallel over <=64 edges, each computes the 4 per-head exp-weights
//     ONCE per edge (not per lane), accumulates per-lane float4 denominator,
//     stashes {w[4], src<<8} in LDS.
//  B: 8-deep unrolled aggregation: per edge just 2 ds_reads + 1 gather + 2 FMA.
// Denominator reduced once per node at the end (unnormalized accumulate).
__global__ __launch_bounds__(256) void k_attn(const uint* __restrict__ hb,
                                              const float* __restrict__ es,
                                              const float* __restrict__ ed,
                                              const int* __restrict__ rowstart,
                                              const int* __restrict__ col,
                                              const float* __restrict__ bias,
                                              float* __restrict__ outp, int do_relu) {
  __shared__ float swv[4][4 * 65];   // [wave][head*65 + edge] (65: bank-stagger)
  __shared__ int   ssc[4][64];       // [wave][edge] = src<<8 (byte offset of h row)
  int lane = threadIdx.x & 63;
  int wv = threadIdx.x >> 6;
  int n = blockIdx.x * 4 + wv;
  if (n >= N_NODES) return;
  int s = rowstart[n], t = rowstart[n + 1];
  int hh = lane >> 4;          // head of this lane's 2 channels
  int c0 = lane * 2;
  float4 edv = *(const float4*)&ed[n * 4];
  const char* hbb = (const char*)hb + (uint)lane * 4u;
  const char* esb = (const char*)es;
  const float* wbase = &swv[wv][hh * 65];
  const int* scb = ssc[wv];

  float4 denv = make_float4(0.f, 0.f, 0.f, 0.f);
  float a0 = 0.f, a1 = 0.f, b0 = 0.f, b1 = 0.f;

  for (int base = s; base < t; base += 64) {
    int nthis = t - base; if (nthis > 64) nthis = 64;
    // ---- phase A ----
    if (lane < nthis) {
      int sc = col[base + lane];
      float4 esv = *(const float4*)(esb + ((uint)sc << 4));
      float w0 = __expf(lrelu(esv.x + edv.x));
      float w1 = __expf(lrelu(esv.y + edv.y));
      float w2 = __expf(lrelu(esv.z + edv.z));
      float w3 = __expf(lrelu(esv.w + edv.w));
      denv.x += w0; denv.y += w1; denv.z += w2; denv.w += w3;
      swv[wv][0 * 65 + lane] = w0;
      swv[wv][1 * 65 + lane] = w1;
      swv[wv][2 * 65 + lane] = w2;
      swv[wv][3 * 65 + lane] = w3;
      ssc[wv][lane] = sc << 8;
    }
    asm volatile("s_waitcnt lgkmcnt(0)" ::: "memory");
    // ---- phase B ----
    int i = 0;
    for (; i + 8 <= nthis; i += 8) {
      float w[8]; int so[8];
      #pragma unroll
      for (int u = 0; u < 8; ++u) { w[u] = wbase[i + u]; so[u] = scb[i + u]; }
      uint hu[8];
      #pragma unroll
      for (int u = 0; u < 8; ++u) hu[u] = *(const uint*)(hbb + (uint)so[u]);
      #pragma unroll
      for (int u = 0; u < 8; ++u) {
        if (u & 1) { b0 = fmaf(w[u], bf_lo(hu[u]), b0); b1 = fmaf(w[u], bf_hi(hu[u]), b1); }
        else       { a0 = fmaf(w[u], bf_lo(hu[u]), a0); a1 = fmaf(w[u], bf_hi(hu[u]), a1); }
      }
    }
    for (; i < nthis; ++i) {
      float w = wbase[i]; int so = scb[i];
      uint u = *(const uint*)(hbb + (uint)so);
      a0 = fmaf(w, bf_lo(u), a0);
      a1 = fmaf(w, bf_hi(u), a1);
    }
  }
  a0 += b0; a1 += b1;
  // reduce denominator across lanes (once per node)
  #pragma unroll
  for (int off = 1; off < 64; off <<= 1) {
    denv.x += __shfl_xor(denv.x, off);
    denv.y += __shfl_xor(denv.y, off);
    denv.z += __shfl_xor(denv.z, off);
    denv.w += __shfl_xor(denv.w, off);
  }
  float den = (hh & 2) ? ((hh & 1) ? denv.w : denv.z) : ((hh & 1) ? denv.y : denv.x);
  float inv = 1.0f / (den + 1e-16f);
  float o0 = a0 * inv + bias[c0];
  float o1 = a1 * inv + bias[c0 + 1];
  if (do_relu) { o0 = fmaxf(o0, 0.f); o1 = fmaxf(o1, 0.f); }
  *(float2*)&outp[(size_t)n * 128 + c0] = make_float2(o0, o1);
}

// one block per graph: mean-pool (binary search on sorted batch) + 128->4 classifier
__global__ __launch_bounds__(128) void k_poolcls(const float* __restrict__ out2,
                                                 const int* __restrict__ batch,
                                                 const float* __restrict__ wc,
                                                 const float* __restrict__ bc,
                                                 float* __restrict__ y) {
  int b = blockIdx.x;
  int c = threadIdx.x;
  int lo = 0, hi = N_NODES;
  while (lo < hi) { int mid = (lo + hi) >> 1; if (batch[mid] < b) lo = mid + 1; else hi = mid; }
  int s = lo;
  lo = s; hi = N_NODES;
  while (lo < hi) { int mid = (lo + hi) >> 1; if (batch[mid] < b + 1) lo = mid + 1; else hi = mid; }
  int e = lo;
  float acc0 = 0.f, acc1 = 0.f, acc2 = 0.f, acc3 = 0.f;
  int nidx = s;
  for (; nidx + 4 <= e; nidx += 4) {
    acc0 += out2[(size_t)nidx * 128 + c];
    acc1 += out2[(size_t)(nidx + 1) * 128 + c];
    acc2 += out2[(size_t)(nidx + 2) * 128 + c];
    acc3 += out2[(size_t)(nidx + 3) * 128 + c];
  }
  for (; nidx < e; ++nidx) acc0 += out2[(size_t)nidx * 128 + c];
  float acc = (acc0 + acc1) + (acc2 + acc3);
  float cnt = (float)(e - s);
  float pooled = acc / fmaxf(cnt, 1.0f);
  float4 wrow = *(const float4*)&wc[c * 4];
  float wj[4] = {wrow.x, wrow.y, wrow.z, wrow.w};
  __shared__ float red[128];
  #pragma unroll
  for (int j = 0; j < 4; ++j) {
    red[c] = pooled * wj[j];
    __syncthreads();
    for (int off = 64; off > 0; off >>= 1) {
      if (c < off) red[c] += red[c + off];
      __syncthreads();
    }
    if (c == 0) y[b * 4 + j] = red[0] + bc[j];
    __syncthreads();
  }
}

extern "C" void kernel_launch(void* const* d_in, const int* in_sizes, int n_in,
                              void* d_out, int out_size, void* d_ws, size_t ws_size,
                              hipStream_t stream) {
  const float* x    = (const float*)d_in[0];
  const int*   ei   = (const int*)d_in[1];
  const int*   batch= (const int*)d_in[2];
  const float* w1   = (const float*)d_in[3];
  const float* as1  = (const float*)d_in[4];
  const float* ad1  = (const float*)d_in[5];
  const float* b1   = (const float*)d_in[6];
  const float* w2   = (const float*)d_in[7];
  const float* as2  = (const float*)d_in[8];
  const float* ad2  = (const float*)d_in[9];
  const float* b2   = (const float*)d_in[10];
  const float* wc   = (const float*)d_in[11];
  const float* bc   = (const float*)d_in[12];
  float* y = (float*)d_out;

  char* ws = (char*)d_ws;
  size_t o = 0;
  auto take = [&](size_t bytes) { void* p = ws + o; o = (o + bytes + 255) & ~(size_t)255; return p; };
  uint*  hbu      = (uint*)take((size_t)N_NODES * 64 * 4);     // bf16 h, packed 2/word
  float* obuf     = (float*)take((size_t)N_NODES * HCH * 4);   // fp32 layer outputs
  float* es       = (float*)take((size_t)N_NODES * 4 * 4);
  float* ed       = (float*)take((size_t)N_NODES * 4 * 4);
  int*   deg      = (int*)take((size_t)N_NODES * 4);
  int*   offs     = (int*)take((size_t)EPLUS * 4);
  int*   rowstart = (int*)take((size_t)(N_NODES + 1) * 4);
  int*   col      = (int*)take((size_t)EPLUS * 4);
  int*   bsum     = (int*)take(64 * 4);

  const int GE8 = (EPLUS + 2047) / 2048;     // 8 edges per thread
  const int GN  = (N_NODES + 255) / 256;
  const int GN1 = (N_NODES + 1 + 255) / 256;
  const int GW  = N_NODES / 4;               // 12500 wave-per-node
  const int GG  = (N_NODES + 127) / 128;     // 391 gemm blocks

  // ---- CSR build ----
  k_zero_i32<<<GN, 256, 0, stream>>>(deg, N_NODES);
  k_degoff<<<GE8, 256, 0, stream>>>(ei, deg, offs);
  k_scan1<<<NBLK_SCAN, 256, 0, stream>>>(deg, rowstart, bsum);
  k_scan2<<<1, 64, 0, stream>>>(bsum, NBLK_SCAN);
  k_scan3<<<GN1, 256, 0, stream>>>(rowstart, bsum);
  k_fill2<<<GE8, 256, 0, stream>>>(ei, rowstart, offs, col);

  // ---- layer 1 ----
  k_gemm_fused<<<GG, 256, 0, stream>>>(x, w1, as1, ad1, hbu, es, ed);
  k_attn<<<GW, 256, 0, stream>>>(hbu, es, ed, rowstart, col, b1, obuf, 1);

  // ---- layer 2 ----
  k_gemm_fused<<<GG, 256, 0, stream>>>(obuf, w2, as2, ad2, hbu, es, ed);
  k_attn<<<GW, 256, 0, stream>>>(hbu, es, ed, rowstart, col, b2, obuf, 0);

  // ---- pool + classifier ----
  k_poolcls<<<NB, 128, 0, stream>>>(obuf, batch, wc, bc, y);
}

// Round 5
// 315.323 us; speedup vs baseline: 2.2126x; 1.0205x over previous
//
#include <hip/hip_runtime.h>

#define N_NODES 50000
#define N_EDGES 1600000
#define EPLUS   1650000   // edges + self loops
#define HCH 128           // hidden channels (H*C)
#define NB 512            // graphs
#define NCLS 4
#define NBLK_SCAN 49      // ceil(50000/1024)
#define NCOPY 8           // counter replicas (contention /8; aligns with XCD round-robin)

typedef unsigned int uint;

__device__ __forceinline__ float lrelu(float v) { return v > 0.f ? v : 0.2f * v; }
__device__ __forceinline__ float bf_lo(uint u) { return __uint_as_float(u << 16); }
__device__ __forceinline__ float bf_hi(uint u) { return __uint_as_float(u & 0xffff0000u); }

__global__ void k_zero_i32(int* p, int n) {
  int i = blockIdx.x * 256 + threadIdx.x;
  if (i < n) p[i] = 0;
}

// degree + within-copy offset in ONE atomic pass. Copy c = blockIdx&7:
// concurrent blocks hit different counter replicas -> ~8x less same-address
// serialization; 4 edges/thread with grid 1612 keeps occupancy ~50%.
__global__ void k_degoff(const int* __restrict__ ei, int* __restrict__ cnt,
                         int* __restrict__ offs) {
  int c = blockIdx.x & (NCOPY - 1);
  int* mycnt = cnt + c * N_NODES;
  int i0 = blockIdx.x * 1024 + threadIdx.x;
  #pragma unroll
  for (int u = 0; u < 4; ++u) {
    int e = i0 + u * 256;
    if (e < EPLUS) {
      int dst = (e < N_EDGES) ? ei[N_EDGES + e] : (e - N_EDGES);
      offs[e] = atomicAdd(&mycnt[dst], 1);
    }
  }
}

// per-node: sum the 8 copies (-> degree), record within-node copy-exclusive
// prefix into base[c][n]; then block-scan degrees for rowstart partials.
__global__ __launch_bounds__(256) void k_scan1(const int* __restrict__ cnt,
                                               int* __restrict__ base,
                                               int* __restrict__ rowstart,
                                               int* __restrict__ bsum) {
  __shared__ int sm[256];
  int t = threadIdx.x;
  int nb = blockIdx.x * 1024 + t * 4;
  int tot[4] = {0, 0, 0, 0};
  #pragma unroll
  for (int j = 0; j < 4; ++j) {
    int n = nb + j;
    if (n < N_NODES) {
      int run = 0;
      #pragma unroll
      for (int c = 0; c < NCOPY; ++c) {
        int v = cnt[c * N_NODES + n];
        base[c * N_NODES + n] = run;   // within-node exclusive prefix over copies
        run += v;
      }
      tot[j] = run;
    }
  }
  int s = tot[0] + tot[1] + tot[2] + tot[3];
  sm[t] = s;
  __syncthreads();
  for (int off = 1; off < 256; off <<= 1) {
    int xv = (t >= off) ? sm[t - off] : 0;
    __syncthreads();
    sm[t] += xv;
    __syncthreads();
  }
  int excl = sm[t] - s;
  if (t == 255) bsum[blockIdx.x] = sm[255];
  int run = excl;
  #pragma unroll
  for (int j = 0; j < 4; ++j) {
    int n = nb + j;
    if (n < N_NODES) { rowstart[n] = run; run += tot[j]; }
  }
}

__global__ void k_scan2(int* bsum, int nblk) {
  if (threadIdx.x == 0 && blockIdx.x == 0) {
    int acc = 0;
    for (int i = 0; i < nblk; ++i) { int v = bsum[i]; bsum[i] = acc; acc += v; }
  }
}

// finalize rowstart and add it into the 8 per-copy bases.
__global__ void k_scan3(int* __restrict__ rowstart, const int* __restrict__ bsum,
                        int* __restrict__ base) {
  int i = blockIdx.x * 256 + threadIdx.x;
  if (i < N_NODES) {
    int rs = rowstart[i] + bsum[i >> 10];
    rowstart[i] = rs;
    #pragma unroll
    for (int c = 0; c < NCOPY; ++c) base[c * N_NODES + i] += rs;
  } else if (i == N_NODES) {
    rowstart[N_NODES] = EPLUS;
  }
}

// no atomics: pos = base[copy][dst] + offs[e]. MUST use the same grid and
// thread->edge mapping as k_degoff (copy recomputed from blockIdx).
__global__ void k_fill2(const int* __restrict__ ei, const int* __restrict__ base,
                        const int* __restrict__ offs, int* __restrict__ col) {
  int c = blockIdx.x & (NCOPY - 1);
  const int* mybase = base + c * N_NODES;
  int i0 = blockIdx.x * 1024 + threadIdx.x;
  #pragma unroll
  for (int u = 0; u < 4; ++u) {
    int e = i0 + u * 256;
    if (e < EPLUS) {
      int src, dst;
      if (e < N_EDGES) { src = ei[e]; dst = ei[N_EDGES + e]; }
      else { src = dst = e - N_EDGES; }
      col[mybase[dst] + offs[e]] = src;
    }
  }
}

// Y = X[N,128] @ W[128,128] (fp32 vector ALU). Epilogue: bf16-pack h into hbu,
// and compute es/ed (per-head dots with a_src/a_dst) from the fp32 accumulators.
__global__ __launch_bounds__(256) void k_gemm_fused(const float* __restrict__ X,
                                                    const float* __restrict__ W,
                                                    const float* __restrict__ asrc,
                                                    const float* __restrict__ adst,
                                                    uint* __restrict__ hbu,
                                                    float* __restrict__ es,
                                                    float* __restrict__ ed) {
  __shared__ float As[128][36];
  __shared__ float Bs[32][132];
  int tid = threadIdx.x;
  int r0 = blockIdx.x * 128;
  int tm = tid >> 4;   // 0..15 -> rows tm + 16*i
  int tn = tid & 15;   // 0..15 -> cols tn*8 .. +7  (all within head tn>>2)
  float acc[8][8];
  #pragma unroll
  for (int i = 0; i < 8; ++i)
    #pragma unroll
    for (int j = 0; j < 8; ++j) acc[i][j] = 0.f;

  for (int kc = 0; kc < 128; kc += 32) {
    #pragma unroll
    for (int i = 0; i < 4; ++i) {          // X tile 128x32
      int q = tid + 256 * i;
      int row = q >> 3;
      int kq = (q & 7) << 2;
      int gr = r0 + row;
      float4 v = make_float4(0.f, 0.f, 0.f, 0.f);
      if (gr < N_NODES) v = *(const float4*)&X[(size_t)gr * 128 + kc + kq];
      *(float4*)&As[row][kq] = v;
    }
    #pragma unroll
    for (int i = 0; i < 4; ++i) {          // W tile 32x128
      int q = tid + 256 * i;
      int kr = q >> 5;
      int nq = (q & 31) << 2;
      float4 v = *(const float4*)&W[(size_t)(kc + kr) * 128 + nq];
      *(float4*)&Bs[kr][nq] = v;
    }
    __syncthreads();
    #pragma unroll 8
    for (int k = 0; k < 32; ++k) {
      float a[8];
      #pragma unroll
      for (int i = 0; i < 8; ++i) a[i] = As[tm + 16 * i][k];
      float4 bq0 = *(const float4*)&Bs[k][tn * 8];
      float4 bq1 = *(const float4*)&Bs[k][tn * 8 + 4];
      float b[8] = {bq0.x, bq0.y, bq0.z, bq0.w, bq1.x, bq1.y, bq1.z, bq1.w};
      #pragma unroll
      for (int i = 0; i < 8; ++i)
        #pragma unroll
        for (int j = 0; j < 8; ++j)
          acc[i][j] = fmaf(a[i], b[j], acc[i][j]);
    }
    __syncthreads();
  }

  // epilogue: bf16 pack + per-head attention dots (exact fp32)
  float av_s[8], av_d[8];
  #pragma unroll
  for (int j = 0; j < 8; ++j) { av_s[j] = asrc[tn * 8 + j]; av_d[j] = adst[tn * 8 + j]; }
  int head = tn >> 2;
  #pragma unroll
  for (int i = 0; i < 8; ++i) {
    int row = r0 + tm + 16 * i;
    float ps = 0.f, pd = 0.f;
    uint us[8];
    #pragma unroll
    for (int j = 0; j < 8; ++j) {
      float v = acc[i][j];
      ps = fmaf(v, av_s[j], ps);
      pd = fmaf(v, av_d[j], pd);
      uint b = __float_as_uint(v);
      us[j] = (b + 0x7fffu + ((b >> 16) & 1u)) >> 16;   // RNE to bf16
    }
    // reduce over the 4 threads (same tm, same head): lanes base-aligned to 4
    ps += __shfl_xor(ps, 1); ps += __shfl_xor(ps, 2);
    pd += __shfl_xor(pd, 1); pd += __shfl_xor(pd, 2);
    if (row < N_NODES) {
      uint4 p;
      p.x = us[0] | (us[1] << 16);
      p.y = us[2] | (us[3] << 16);
      p.z = us[4] | (us[5] << 16);
      p.w = us[6] | (us[7] << 16);
      *(uint4*)&hbu[(size_t)row * 64 + tn * 4] = p;
      if ((tn & 3) == 0) {
        es[row * 4 + head] = ps;
        ed[row * 4 + head] = pd;
      }
    }
  }
}

// one wave per destination node. Two-phase via LDS:
//  A: lanes parallel over <=64 edges, each computes the 4 per-head exp-weights
//     ONCE per edge, accumulates per-lane float4 denominator, stashes
//     {w[4], src<<8} in LDS.
//  B: 8-deep unrolled aggregation: per edge 2 ds_reads + 1 gather + 2 FMA.
__global__ __launch_bounds__(256) void k_attn(const uint* __restrict__ hb,
                                              const float* __restrict__ es,
                                              const float* __restrict__ ed,
                                              const int* __restrict__ rowstart,
                                              const int* __restrict__ col,
                                              const float* __restrict__ bias,
                                              float* __restrict__ outp, int do_relu) {
  __shared__ float swv[4][4 * 65];   // [wave][head*65 + edge] (65: bank-stagger)
  __shared__ int   ssc[4][64];       // [wave][edge] = src<<8 (byte offset of h row)
  int lane = threadIdx.x & 63;
  int wv = threadIdx.x >> 6;
  int n = blockIdx.x * 4 + wv;
  if (n >= N_NODES) return;
  int s = rowstart[n], t = rowstart[n + 1];
  int hh = lane >> 4;          // head of this lane's 2 channels
  int c0 = lane * 2;
  float4 edv = *(const float4*)&ed[n * 4];
  const char* hbb = (const char*)hb + (uint)lane * 4u;
  const char* esb = (const char*)es;
  const float* wbase = &swv[wv][hh * 65];
  const int* scb = ssc[wv];

  float4 denv = make_float4(0.f, 0.f, 0.f, 0.f);
  float a0 = 0.f, a1 = 0.f, b0 = 0.f, b1 = 0.f;

  for (int base = s; base < t; base += 64) {
    int nthis = t - base; if (nthis > 64) nthis = 64;
    // ---- phase A ----
    if (lane < nthis) {
      int sc = col[base + lane];
      float4 esv = *(const float4*)(esb + ((uint)sc << 4));
      float w0 = __expf(lrelu(esv.x + edv.x));
      float w1 = __expf(lrelu(esv.y + edv.y));
      float w2 = __expf(lrelu(esv.z + edv.z));
      float w3 = __expf(lrelu(esv.w + edv.w));
      denv.x += w0; denv.y += w1; denv.z += w2; denv.w += w3;
      swv[wv][0 * 65 + lane] = w0;
      swv[wv][1 * 65 + lane] = w1;
      swv[wv][2 * 65 + lane] = w2;
      swv[wv][3 * 65 + lane] = w3;
      ssc[wv][lane] = sc << 8;
    }
    asm volatile("s_waitcnt lgkmcnt(0)" ::: "memory");
    // ---- phase B ----
    int i = 0;
    for (; i + 8 <= nthis; i += 8) {
      float w[8]; int so[8];
      #pragma unroll
      for (int u = 0; u < 8; ++u) { w[u] = wbase[i + u]; so[u] = scb[i + u]; }
      uint hu[8];
      #pragma unroll
      for (int u = 0; u < 8; ++u) hu[u] = *(const uint*)(hbb + (uint)so[u]);
      #pragma unroll
      for (int u = 0; u < 8; ++u) {
        if (u & 1) { b0 = fmaf(w[u], bf_lo(hu[u]), b0); b1 = fmaf(w[u], bf_hi(hu[u]), b1); }
        else       { a0 = fmaf(w[u], bf_lo(hu[u]), a0); a1 = fmaf(w[u], bf_hi(hu[u]), a1); }
      }
    }
    for (; i < nthis; ++i) {
      float w = wbase[i]; int so = scb[i];
      uint u = *(const uint*)(hbb + (uint)so);
      a0 = fmaf(w, bf_lo(u), a0);
      a1 = fmaf(w, bf_hi(u), a1);
    }
  }
  a0 += b0; a1 += b1;
  // reduce denominator across lanes (once per node)
  #pragma unroll
  for (int off = 1; off < 64; off <<= 1) {
    denv.x += __shfl_xor(denv.x, off);
    denv.y += __shfl_xor(denv.y, off);
    denv.z += __shfl_xor(denv.z, off);
    denv.w += __shfl_xor(denv.w, off);
  }
  float den = (hh & 2) ? ((hh & 1) ? denv.w : denv.z) : ((hh & 1) ? denv.y : denv.x);
  float inv = 1.0f / (den + 1e-16f);
  float o0 = a0 * inv + bias[c0];
  float o1 = a1 * inv + bias[c0 + 1];
  if (do_relu) { o0 = fmaxf(o0, 0.f); o1 = fmaxf(o1, 0.f); }
  *(float2*)&outp[(size_t)n * 128 + c0] = make_float2(o0, o1);
}

// one block per graph: mean-pool (binary search on sorted batch) + 128->4 classifier
__global__ __launch_bounds__(128) void k_poolcls(const float* __restrict__ out2,
                                                 const int* __restrict__ batch,
                                                 const float* __restrict__ wc,
                                                 const float* __restrict__ bc,
                                                 float* __restrict__ y) {
  int b = blockIdx.x;
  int c = threadIdx.x;
  int lo = 0, hi = N_NODES;
  while (lo < hi) { int mid = (lo + hi) >> 1; if (batch[mid] < b) lo = mid + 1; else hi = mid; }
  int s = lo;
  lo = s; hi = N_NODES;
  while (lo < hi) { int mid = (lo + hi) >> 1; if (batch[mid] < b + 1) lo = mid + 1; else hi = mid; }
  int e = lo;
  float acc0 = 0.f, acc1 = 0.f, acc2 = 0.f, acc3 = 0.f;
  int nidx = s;
  for (; nidx + 4 <= e; nidx += 4) {
    acc0 += out2[(size_t)nidx * 128 + c];
    acc1 += out2[(size_t)(nidx + 1) * 128 + c];
    acc2 += out2[(size_t)(nidx + 2) * 128 + c];
    acc3 += out2[(size_t)(nidx + 3) * 128 + c];
  }
  for (; nidx < e; ++nidx) acc0 += out2[(size_t)nidx * 128 + c];
  float acc = (acc0 + acc1) + (acc2 + acc3);
  float cnt = (float)(e - s);
  float pooled = acc / fmaxf(cnt, 1.0f);
  float4 wrow = *(const float4*)&wc[c * 4];
  float wj[4] = {wrow.x, wrow.y, wrow.z, wrow.w};
  __shared__ float red[128];
  #pragma unroll
  for (int j = 0; j < 4; ++j) {
    red[c] = pooled * wj[j];
    __syncthreads();
    for (int off = 64; off > 0; off >>= 1) {
      if (c < off) red[c] += red[c + off];
      __syncthreads();
    }
    if (c == 0) y[b * 4 + j] = red[0] + bc[j];
    __syncthreads();
  }
}

extern "C" void kernel_launch(void* const* d_in, const int* in_sizes, int n_in,
                              void* d_out, int out_size, void* d_ws, size_t ws_size,
                              hipStream_t stream) {
  const float* x    = (const float*)d_in[0];
  const int*   ei   = (const int*)d_in[1];
  const int*   batch= (const int*)d_in[2];
  const float* w1   = (const float*)d_in[3];
  const float* as1  = (const float*)d_in[4];
  const float* ad1  = (const float*)d_in[5];
  const float* b1   = (const float*)d_in[6];
  const float* w2   = (const float*)d_in[7];
  const float* as2  = (const float*)d_in[8];
  const float* ad2  = (const float*)d_in[9];
  const float* b2   = (const float*)d_in[10];
  const float* wc   = (const float*)d_in[11];
  const float* bc   = (const float*)d_in[12];
  float* y = (float*)d_out;

  char* ws = (char*)d_ws;
  size_t o = 0;
  auto take = [&](size_t bytes) { void* p = ws + o; o = (o + bytes + 255) & ~(size_t)255; return p; };
  uint*  hbu      = (uint*)take((size_t)N_NODES * 64 * 4);        // bf16 h, packed 2/word
  float* obuf     = (float*)take((size_t)N_NODES * HCH * 4);      // fp32 layer outputs
  float* es       = (float*)take((size_t)N_NODES * 4 * 4);
  float* ed       = (float*)take((size_t)N_NODES * 4 * 4);
  int*   cnt      = (int*)take((size_t)NCOPY * N_NODES * 4);      // replicated counters
  int*   base     = (int*)take((size_t)NCOPY * N_NODES * 4);      // per-copy fill bases
  int*   offs     = (int*)take((size_t)EPLUS * 4);
  int*   rowstart = (int*)take((size_t)(N_NODES + 1) * 4);
  int*   col      = (int*)take((size_t)EPLUS * 4);
  int*   bsum     = (int*)take(64 * 4);

  const int GE4 = (EPLUS + 1023) / 1024;        // 1612 blocks, 4 edges/thread
  const int GNC = (NCOPY * N_NODES + 255) / 256;
  const int GN1 = (N_NODES + 1 + 255) / 256;
  const int GW  = N_NODES / 4;                  // 12500 wave-per-node
  const int GG  = (N_NODES + 127) / 128;        // 391 gemm blocks

  // ---- CSR build ----
  k_zero_i32<<<GNC, 256, 0, stream>>>(cnt, NCOPY * N_NODES);
  k_degoff<<<GE4, 256, 0, stream>>>(ei, cnt, offs);
  k_scan1<<<NBLK_SCAN, 256, 0, stream>>>(cnt, base, rowstart, bsum);
  k_scan2<<<1, 64, 0, stream>>>(bsum, NBLK_SCAN);
  k_scan3<<<GN1, 256, 0, stream>>>(rowstart, bsum, base);
  k_fill2<<<GE4, 256, 0, stream>>>(ei, base, offs, col);

  // ---- layer 1 ----
  k_gemm_fused<<<GG, 256, 0, stream>>>(x, w1, as1, ad1, hbu, es, ed);
  k_attn<<<GW, 256, 0, stream>>>(hbu, es, ed, rowstart, col, b1, obuf, 1);

  // ---- layer 2 ----
  k_gemm_fused<<<GG, 256, 0, stream>>>(obuf, w2, as2, ad2, hbu, es, ed);
  k_attn<<<GW, 256, 0, stream>>>(hbu, es, ed, rowstart, col, b2, obuf, 0);

  // ---- pool + classifier ----
  k_poolcls<<<NB, 128, 0, stream>>>(obuf, batch, wc, bc, y);
}

// Round 6
// 271.244 us; speedup vs baseline: 2.5721x; 1.1625x over previous
//
#include <hip/hip_runtime.h>

#define N_NODES 50000
#define N_EDGES 1600000
#define EPLUS   1650000   // edges + self loops
#define HCH 128           // hidden channels (H*C)
#define NB 512            // graphs
#define NCLS 4
#define NBUCK 782         // ceil(N_NODES/64); bucket = dst>>6
#define NSB 256           // scatter blocks for passes A/C
#define PCHUNK 6446       // ceil(EPLUS/NSB)

typedef unsigned int uint;

__device__ __forceinline__ float lrelu(float v) { return v > 0.f ? v : 0.2f * v; }
__device__ __forceinline__ float bf_lo(uint u) { return __uint_as_float(u << 16); }
__device__ __forceinline__ float bf_hi(uint u) { return __uint_as_float(u & 0xffff0000u); }

// ---- pass A: per-block bucket histogram (LDS atomics only) ----
__global__ __launch_bounds__(256) void k_pA(const int* __restrict__ ei,
                                            int* __restrict__ M) {
  __shared__ int lh[NBUCK];
  for (int k = threadIdx.x; k < NBUCK; k += 256) lh[k] = 0;
  __syncthreads();
  int lo = blockIdx.x * PCHUNK;
  int hi = lo + PCHUNK; if (hi > EPLUS) hi = EPLUS;
  for (int e = lo + threadIdx.x; e < hi; e += 256) {
    int dst = (e < N_EDGES) ? ei[N_EDGES + e] : (e - N_EDGES);
    atomicAdd(&lh[dst >> 6], 1);
  }
  __syncthreads();
  for (int k = threadIdx.x; k < NBUCK; k += 256)
    M[blockIdx.x * NBUCK + k] = lh[k];
}

// ---- pass B: column prefix over blocks + bucket exclusive scan (1 block) ----
__global__ __launch_bounds__(1024) void k_pB(int* __restrict__ M,
                                             int* __restrict__ bucketstart) {
  __shared__ int sm[1024];
  int k = threadIdx.x;
  int tot = 0;
  if (k < NBUCK) {
    int run = 0;
    for (int b = 0; b < NSB; ++b) {
      int v = M[b * NBUCK + k];
      M[b * NBUCK + k] = run;     // within-bucket, over-blocks exclusive prefix
      run += v;
    }
    tot = run;
  }
  sm[k] = tot;
  __syncthreads();
  for (int off = 1; off < 1024; off <<= 1) {
    int v = (k >= off) ? sm[k - off] : 0;
    __syncthreads();
    sm[k] += v;
    __syncthreads();
  }
  if (k < NBUCK) {
    bucketstart[k] = sm[k] - tot;               // exclusive
    if (k == NBUCK - 1) bucketstart[NBUCK] = sm[k];  // = EPLUS
  }
}

// ---- pass C: scatter edges into bucket-grouped order (LDS atomics only) ----
__global__ __launch_bounds__(256) void k_pC(const int* __restrict__ ei,
                                            const int* __restrict__ M,
                                            const int* __restrict__ bucketstart,
                                            uint* __restrict__ part) {
  __shared__ int lbase[NBUCK];
  __shared__ int lc[NBUCK];
  for (int k = threadIdx.x; k < NBUCK; k += 256) {
    lbase[k] = bucketstart[k] + M[blockIdx.x * NBUCK + k];
    lc[k] = 0;
  }
  __syncthreads();
  int lo = blockIdx.x * PCHUNK;
  int hi = lo + PCHUNK; if (hi > EPLUS) hi = EPLUS;
  for (int e = lo + threadIdx.x; e < hi; e += 256) {
    int src, dst;
    if (e < N_EDGES) { src = ei[e]; dst = ei[N_EDGES + e]; }
    else { src = dst = e - N_EDGES; }
    int b = dst >> 6;
    int p = lbase[b] + atomicAdd(&lc[b], 1);
    part[p] = (uint)src | ((uint)dst << 16);   // both ids < 2^16
  }
}

// ---- pass D: per-bucket fine CSR (64 dsts) via LDS counters + wave scan ----
__global__ __launch_bounds__(256) void k_pD(const uint* __restrict__ part,
                                            const int* __restrict__ bucketstart,
                                            int* __restrict__ rowstart,
                                            int* __restrict__ col) {
  __shared__ int dcnt[64], dstart[64], dc2[64];
  int b = blockIdx.x;
  int n0 = bucketstart[b], n1 = bucketstart[b + 1];
  int t = threadIdx.x;
  if (t < 64) { dcnt[t] = 0; dc2[t] = 0; }
  __syncthreads();
  for (int i = n0 + t; i < n1; i += 256)
    atomicAdd(&dcnt[(part[i] >> 16) & 63], 1);
  __syncthreads();
  if (t < 64) {
    int v = dcnt[t];
    int run = v;
    #pragma unroll
    for (int off = 1; off < 64; off <<= 1) {
      int u = __shfl_up(run, off);
      if (t >= off) run += u;
    }
    dstart[t] = run - v;   // exclusive within bucket
    int node = b * 64 + t;
    if (node < N_NODES) rowstart[node] = n0 + run - v;
  }
  if (b == NBUCK - 1 && t == 0) rowstart[N_NODES] = n1;  // = EPLUS
  __syncthreads();
  for (int i = n0 + t; i < n1; i += 256) {
    uint pr = part[i];
    int loc = (pr >> 16) & 63;
    int pos = n0 + dstart[loc] + atomicAdd(&dc2[loc], 1);
    col[pos] = (int)(pr & 0xffffu);
  }
}

// Y = X[N,128] @ W[128,128] (fp32 vector ALU). Epilogue: bf16-pack h into hbu,
// and compute es/ed (per-head dots with a_src/a_dst) from the fp32 accumulators.
__global__ __launch_bounds__(256) void k_gemm_fused(const float* __restrict__ X,
                                                    const float* __restrict__ W,
                                                    const float* __restrict__ asrc,
                                                    const float* __restrict__ adst,
                                                    uint* __restrict__ hbu,
                                                    float* __restrict__ es,
                                                    float* __restrict__ ed) {
  __shared__ float As[128][36];
  __shared__ float Bs[32][132];
  int tid = threadIdx.x;
  int r0 = blockIdx.x * 128;
  int tm = tid >> 4;   // 0..15 -> rows tm + 16*i
  int tn = tid & 15;   // 0..15 -> cols tn*8 .. +7  (all within head tn>>2)
  float acc[8][8];
  #pragma unroll
  for (int i = 0; i < 8; ++i)
    #pragma unroll
    for (int j = 0; j < 8; ++j) acc[i][j] = 0.f;

  for (int kc = 0; kc < 128; kc += 32) {
    #pragma unroll
    for (int i = 0; i < 4; ++i) {          // X tile 128x32
      int q = tid + 256 * i;
      int row = q >> 3;
      int kq = (q & 7) << 2;
      int gr = r0 + row;
      float4 v = make_float4(0.f, 0.f, 0.f, 0.f);
      if (gr < N_NODES) v = *(const float4*)&X[(size_t)gr * 128 + kc + kq];
      *(float4*)&As[row][kq] = v;
    }
    #pragma unroll
    for (int i = 0; i < 4; ++i) {          // W tile 32x128
      int q = tid + 256 * i;
      int kr = q >> 5;
      int nq = (q & 31) << 2;
      float4 v = *(const float4*)&W[(size_t)(kc + kr) * 128 + nq];
      *(float4*)&Bs[kr][nq] = v;
    }
    __syncthreads();
    #pragma unroll 8
    for (int k = 0; k < 32; ++k) {
      float a[8];
      #pragma unroll
      for (int i = 0; i < 8; ++i) a[i] = As[tm + 16 * i][k];
      float4 bq0 = *(const float4*)&Bs[k][tn * 8];
      float4 bq1 = *(const float4*)&Bs[k][tn * 8 + 4];
      float b[8] = {bq0.x, bq0.y, bq0.z, bq0.w, bq1.x, bq1.y, bq1.z, bq1.w};
      #pragma unroll
      for (int i = 0; i < 8; ++i)
        #pragma unroll
        for (int j = 0; j < 8; ++j)
          acc[i][j] = fmaf(a[i], b[j], acc[i][j]);
    }
    __syncthreads();
  }

  // epilogue: bf16 pack + per-head attention dots (exact fp32)
  float av_s[8], av_d[8];
  #pragma unroll
  for (int j = 0; j < 8; ++j) { av_s[j] = asrc[tn * 8 + j]; av_d[j] = adst[tn * 8 + j]; }
  int head = tn >> 2;
  #pragma unroll
  for (int i = 0; i < 8; ++i) {
    int row = r0 + tm + 16 * i;
    float ps = 0.f, pd = 0.f;
    uint us[8];
    #pragma unroll
    for (int j = 0; j < 8; ++j) {
      float v = acc[i][j];
      ps = fmaf(v, av_s[j], ps);
      pd = fmaf(v, av_d[j], pd);
      uint b = __float_as_uint(v);
      us[j] = (b + 0x7fffu + ((b >> 16) & 1u)) >> 16;   // RNE to bf16
    }
    // reduce over the 4 threads (same tm, same head): lanes base-aligned to 4
    ps += __shfl_xor(ps, 1); ps += __shfl_xor(ps, 2);
    pd += __shfl_xor(pd, 1); pd += __shfl_xor(pd, 2);
    if (row < N_NODES) {
      uint4 p;
      p.x = us[0] | (us[1] << 16);
      p.y = us[2] | (us[3] << 16);
      p.z = us[4] | (us[5] << 16);
      p.w = us[6] | (us[7] << 16);
      *(uint4*)&hbu[(size_t)row * 64 + tn * 4] = p;
      if ((tn & 3) == 0) {
        es[row * 4 + head] = ps;
        ed[row * 4 + head] = pd;
      }
    }
  }
}

// one wave per destination node. Two-phase via LDS:
//  A: lanes parallel over <=64 edges, each computes the 4 per-head exp-weights
//     ONCE per edge, accumulates per-lane float4 denominator, stashes
//     {w[4], src<<8} in LDS.
//  B: 8-deep unrolled aggregation: per edge 2 ds_reads + 1 gather + 2 FMA.
__global__ __launch_bounds__(256) void k_attn(const uint* __restrict__ hb,
                                              const float* __restrict__ es,
                                              const float* __restrict__ ed,
                                              const int* __restrict__ rowstart,
                                              const int* __restrict__ col,
                                              const float* __restrict__ bias,
                                              float* __restrict__ outp, int do_relu) {
  __shared__ float swv[4][4 * 65];   // [wave][head*65 + edge] (65: bank-stagger)
  __shared__ int   ssc[4][64];       // [wave][edge] = src<<8 (byte offset of h row)
  int lane = threadIdx.x & 63;
  int wv = threadIdx.x >> 6;
  int n = blockIdx.x * 4 + wv;
  if (n >= N_NODES) return;
  int s = rowstart[n], t = rowstart[n + 1];
  int hh = lane >> 4;          // head of this lane's 2 channels
  int c0 = lane * 2;
  float4 edv = *(const float4*)&ed[n * 4];
  const char* hbb = (const char*)hb + (uint)lane * 4u;
  const char* esb = (const char*)es;
  const float* wbase = &swv[wv][hh * 65];
  const int* scb = ssc[wv];

  float4 denv = make_float4(0.f, 0.f, 0.f, 0.f);
  float a0 = 0.f, a1 = 0.f, b0 = 0.f, b1 = 0.f;

  for (int base = s; base < t; base += 64) {
    int nthis = t - base; if (nthis > 64) nthis = 64;
    // ---- phase A ----
    if (lane < nthis) {
      int sc = col[base + lane];
      float4 esv = *(const float4*)(esb + ((uint)sc << 4));
      float w0 = __expf(lrelu(esv.x + edv.x));
      float w1 = __expf(lrelu(esv.y + edv.y));
      float w2 = __expf(lrelu(esv.z + edv.z));
      float w3 = __expf(lrelu(esv.w + edv.w));
      denv.x += w0; denv.y += w1; denv.z += w2; denv.w += w3;
      swv[wv][0 * 65 + lane] = w0;
      swv[wv][1 * 65 + lane] = w1;
      swv[wv][2 * 65 + lane] = w2;
      swv[wv][3 * 65 + lane] = w3;
      ssc[wv][lane] = sc << 8;
    }
    asm volatile("s_waitcnt lgkmcnt(0)" ::: "memory");
    // ---- phase B ----
    int i = 0;
    for (; i + 8 <= nthis; i += 8) {
      float w[8]; int so[8];
      #pragma unroll
      for (int u = 0; u < 8; ++u) { w[u] = wbase[i + u]; so[u] = scb[i + u]; }
      uint hu[8];
      #pragma unroll
      for (int u = 0; u < 8; ++u) hu[u] = *(const uint*)(hbb + (uint)so[u]);
      #pragma unroll
      for (int u = 0; u < 8; ++u) {
        if (u & 1) { b0 = fmaf(w[u], bf_lo(hu[u]), b0); b1 = fmaf(w[u], bf_hi(hu[u]), b1); }
        else       { a0 = fmaf(w[u], bf_lo(hu[u]), a0); a1 = fmaf(w[u], bf_hi(hu[u]), a1); }
      }
    }
    for (; i < nthis; ++i) {
      float w = wbase[i]; int so = scb[i];
      uint u = *(const uint*)(hbb + (uint)so);
      a0 = fmaf(w, bf_lo(u), a0);
      a1 = fmaf(w, bf_hi(u), a1);
    }
  }
  a0 += b0; a1 += b1;
  // reduce denominator across lanes (once per node)
  #pragma unroll
  for (int off = 1; off < 64; off <<= 1) {
    denv.x += __shfl_xor(denv.x, off);
    denv.y += __shfl_xor(denv.y, off);
    denv.z += __shfl_xor(denv.z, off);
    denv.w += __shfl_xor(denv.w, off);
  }
  float den = (hh & 2) ? ((hh & 1) ? denv.w : denv.z) : ((hh & 1) ? denv.y : denv.x);
  float inv = 1.0f / (den + 1e-16f);
  float o0 = a0 * inv + bias[c0];
  float o1 = a1 * inv + bias[c0 + 1];
  if (do_relu) { o0 = fmaxf(o0, 0.f); o1 = fmaxf(o1, 0.f); }
  *(float2*)&outp[(size_t)n * 128 + c0] = make_float2(o0, o1);
}

// one block per graph: mean-pool (binary search on sorted batch) + 128->4 classifier
__global__ __launch_bounds__(128) void k_poolcls(const float* __restrict__ out2,
                                                 const int* __restrict__ batch,
                                                 const float* __restrict__ wc,
                                                 const float* __restrict__ bc,
                                                 float* __restrict__ y) {
  int b = blockIdx.x;
  int c = threadIdx.x;
  int lo = 0, hi = N_NODES;
  while (lo < hi) { int mid = (lo + hi) >> 1; if (batch[mid] < b) lo = mid + 1; else hi = mid; }
  int s = lo;
  lo = s; hi = N_NODES;
  while (lo < hi) { int mid = (lo + hi) >> 1; if (batch[mid] < b + 1) lo = mid + 1; else hi = mid; }
  int e = lo;
  float acc0 = 0.f, acc1 = 0.f, acc2 = 0.f, acc3 = 0.f;
  int nidx = s;
  for (; nidx + 4 <= e; nidx += 4) {
    acc0 += out2[(size_t)nidx * 128 + c];
    acc1 += out2[(size_t)(nidx + 1) * 128 + c];
    acc2 += out2[(size_t)(nidx + 2) * 128 + c];
    acc3 += out2[(size_t)(nidx + 3) * 128 + c];
  }
  for (; nidx < e; ++nidx) acc0 += out2[(size_t)nidx * 128 + c];
  float acc = (acc0 + acc1) + (acc2 + acc3);
  float cnt = (float)(e - s);
  float pooled = acc / fmaxf(cnt, 1.0f);
  float4 wrow = *(const float4*)&wc[c * 4];
  float wj[4] = {wrow.x, wrow.y, wrow.z, wrow.w};
  __shared__ float red[128];
  #pragma unroll
  for (int j = 0; j < 4; ++j) {
    red[c] = pooled * wj[j];
    __syncthreads();
    for (int off = 64; off > 0; off >>= 1) {
      if (c < off) red[c] += red[c + off];
      __syncthreads();
    }
    if (c == 0) y[b * 4 + j] = red[0] + bc[j];
    __syncthreads();
  }
}

extern "C" void kernel_launch(void* const* d_in, const int* in_sizes, int n_in,
                              void* d_out, int out_size, void* d_ws, size_t ws_size,
                              hipStream_t stream) {
  const float* x    = (const float*)d_in[0];
  const int*   ei   = (const int*)d_in[1];
  const int*   batch= (const int*)d_in[2];
  const float* w1   = (const float*)d_in[3];
  const float* as1  = (const float*)d_in[4];
  const float* ad1  = (const float*)d_in[5];
  const float* b1   = (const float*)d_in[6];
  const float* w2   = (const float*)d_in[7];
  const float* as2  = (const float*)d_in[8];
  const float* ad2  = (const float*)d_in[9];
  const float* b2   = (const float*)d_in[10];
  const float* wc   = (const float*)d_in[11];
  const float* bc   = (const float*)d_in[12];
  float* y = (float*)d_out;

  char* ws = (char*)d_ws;
  size_t o = 0;
  auto take = [&](size_t bytes) { void* p = ws + o; o = (o + bytes + 255) & ~(size_t)255; return p; };
  uint*  hbu      = (uint*)take((size_t)N_NODES * 64 * 4);        // bf16 h, packed 2/word
  float* obuf     = (float*)take((size_t)N_NODES * HCH * 4);      // fp32 layer outputs
  float* es       = (float*)take((size_t)N_NODES * 4 * 4);
  float* ed       = (float*)take((size_t)N_NODES * 4 * 4);
  int*   M        = (int*)take((size_t)NSB * NBUCK * 4);          // per-block bucket hist/prefix
  int*   bstart   = (int*)take((size_t)(NBUCK + 1) * 4);
  uint*  part     = (uint*)take((size_t)EPLUS * 4);               // bucket-grouped packed edges
  int*   rowstart = (int*)take((size_t)(N_NODES + 1) * 4);
  int*   col      = (int*)take((size_t)EPLUS * 4);

  const int GW = N_NODES / 4;               // 12500 wave-per-node
  const int GG = (N_NODES + 127) / 128;     // 391 gemm blocks

  // ---- CSR build (no global returning atomics) ----
  k_pA<<<NSB, 256, 0, stream>>>(ei, M);
  k_pB<<<1, 1024, 0, stream>>>(M, bstart);
  k_pC<<<NSB, 256, 0, stream>>>(ei, M, bstart, part);
  k_pD<<<NBUCK, 256, 0, stream>>>(part, bstart, rowstart, col);

  // ---- layer 1 ----
  k_gemm_fused<<<GG, 256, 0, stream>>>(x, w1, as1, ad1, hbu, es, ed);
  k_attn<<<GW, 256, 0, stream>>>(hbu, es, ed, rowstart, col, b1, obuf, 1);

  // ---- layer 2 ----
  k_gemm_fused<<<GG, 256, 0, stream>>>(obuf, w2, as2, ad2, hbu, es, ed);
  k_attn<<<GW, 256, 0, stream>>>(hbu, es, ed, rowstart, col, b2, obuf, 0);

  // ---- pool + classifier ----
  k_poolcls<<<NB, 128, 0, stream>>>(obuf, batch, wc, bc, y);
}

// Round 7
// 268.677 us; speedup vs baseline: 2.5967x; 1.0096x over previous
//
#include <hip/hip_runtime.h>

#define N_NODES 50000
#define N_EDGES 1600000
#define EPLUS   1650000   // edges + self loops
#define HCH 128           // hidden channels (H*C)
#define NB 512            // graphs
#define NCLS 4
#define NBUCK 782         // ceil(N_NODES/64); bucket = dst>>6
#define NSB 256           // scatter blocks for passes A/C
#define PCHUNK 6446       // ceil(EPLUS/NSB)

typedef unsigned int uint;

__device__ __forceinline__ float lrelu(float v) { return v > 0.f ? v : 0.2f * v; }
__device__ __forceinline__ float bf_lo(uint u) { return __uint_as_float(u << 16); }
__device__ __forceinline__ float bf_hi(uint u) { return __uint_as_float(u & 0xffff0000u); }

// ---- pass A: per-block bucket histogram (LDS atomics only) ----
__global__ __launch_bounds__(256) void k_pA(const int* __restrict__ ei,
                                            int* __restrict__ M) {
  __shared__ int lh[NBUCK];
  for (int k = threadIdx.x; k < NBUCK; k += 256) lh[k] = 0;
  __syncthreads();
  int lo = blockIdx.x * PCHUNK;
  int hi = lo + PCHUNK; if (hi > EPLUS) hi = EPLUS;
  for (int e = lo + threadIdx.x; e < hi; e += 256) {
    int dst = (e < N_EDGES) ? ei[N_EDGES + e] : (e - N_EDGES);
    atomicAdd(&lh[dst >> 6], 1);
  }
  __syncthreads();
  for (int k = threadIdx.x; k < NBUCK; k += 256)
    M[blockIdx.x * NBUCK + k] = lh[k];
}

// ---- pass B: column prefix over blocks + bucket exclusive scan (1 block) ----
__global__ __launch_bounds__(1024) void k_pB(int* __restrict__ M,
                                             int* __restrict__ bucketstart) {
  __shared__ int sm[1024];
  int k = threadIdx.x;
  int tot = 0;
  if (k < NBUCK) {
    int run = 0;
    for (int b = 0; b < NSB; ++b) {
      int v = M[b * NBUCK + k];
      M[b * NBUCK + k] = run;     // within-bucket, over-blocks exclusive prefix
      run += v;
    }
    tot = run;
  }
  sm[k] = tot;
  __syncthreads();
  for (int off = 1; off < 1024; off <<= 1) {
    int v = (k >= off) ? sm[k - off] : 0;
    __syncthreads();
    sm[k] += v;
    __syncthreads();
  }
  if (k < NBUCK) {
    bucketstart[k] = sm[k] - tot;               // exclusive
    if (k == NBUCK - 1) bucketstart[NBUCK] = sm[k];  // = EPLUS
  }
}

// ---- pass C: scatter edges into bucket-grouped order (LDS atomics only) ----
__global__ __launch_bounds__(256) void k_pC(const int* __restrict__ ei,
                                            const int* __restrict__ M,
                                            const int* __restrict__ bucketstart,
                                            uint* __restrict__ part) {
  __shared__ int lbase[NBUCK];
  __shared__ int lc[NBUCK];
  for (int k = threadIdx.x; k < NBUCK; k += 256) {
    lbase[k] = bucketstart[k] + M[blockIdx.x * NBUCK + k];
    lc[k] = 0;
  }
  __syncthreads();
  int lo = blockIdx.x * PCHUNK;
  int hi = lo + PCHUNK; if (hi > EPLUS) hi = EPLUS;
  for (int e = lo + threadIdx.x; e < hi; e += 256) {
    int src, dst;
    if (e < N_EDGES) { src = ei[e]; dst = ei[N_EDGES + e]; }
    else { src = dst = e - N_EDGES; }
    int b = dst >> 6;
    int p = lbase[b] + atomicAdd(&lc[b], 1);
    part[p] = (uint)src | ((uint)dst << 16);   // both ids < 2^16
  }
}

// ---- pass D: per-bucket fine CSR (64 dsts) via LDS counters + wave scan ----
__global__ __launch_bounds__(256) void k_pD(const uint* __restrict__ part,
                                            const int* __restrict__ bucketstart,
                                            int* __restrict__ rowstart,
                                            int* __restrict__ col) {
  __shared__ int dcnt[64], dstart[64], dc2[64];
  int b = blockIdx.x;
  int n0 = bucketstart[b], n1 = bucketstart[b + 1];
  int t = threadIdx.x;
  if (t < 64) { dcnt[t] = 0; dc2[t] = 0; }
  __syncthreads();
  for (int i = n0 + t; i < n1; i += 256)
    atomicAdd(&dcnt[(part[i] >> 16) & 63], 1);
  __syncthreads();
  if (t < 64) {
    int v = dcnt[t];
    int run = v;
    #pragma unroll
    for (int off = 1; off < 64; off <<= 1) {
      int u = __shfl_up(run, off);
      if (t >= off) run += u;
    }
    dstart[t] = run - v;   // exclusive within bucket
    int node = b * 64 + t;
    if (node < N_NODES) rowstart[node] = n0 + run - v;
  }
  if (b == NBUCK - 1 && t == 0) rowstart[N_NODES] = n1;  // = EPLUS
  __syncthreads();
  for (int i = n0 + t; i < n1; i += 256) {
    uint pr = part[i];
    int loc = (pr >> 16) & 63;
    int pos = n0 + dstart[loc] + atomicAdd(&dc2[loc], 1);
    col[pos] = (int)(pr & 0xffffu);
  }
}

// Y = X[N,128] @ W[128,128] (fp32 vector ALU). Epilogue: bf16-pack h into hbu,
// and compute es/ed (per-head dots with a_src/a_dst) from the fp32 accumulators.
__global__ __launch_bounds__(256) void k_gemm_fused(const float* __restrict__ X,
                                                    const float* __restrict__ W,
                                                    const float* __restrict__ asrc,
                                                    const float* __restrict__ adst,
                                                    uint* __restrict__ hbu,
                                                    float* __restrict__ es,
                                                    float* __restrict__ ed) {
  __shared__ float As[128][36];
  __shared__ float Bs[32][132];
  int tid = threadIdx.x;
  int r0 = blockIdx.x * 128;
  int tm = tid >> 4;   // 0..15 -> rows tm + 16*i
  int tn = tid & 15;   // 0..15 -> cols tn*8 .. +7  (all within head tn>>2)
  float acc[8][8];
  #pragma unroll
  for (int i = 0; i < 8; ++i)
    #pragma unroll
    for (int j = 0; j < 8; ++j) acc[i][j] = 0.f;

  for (int kc = 0; kc < 128; kc += 32) {
    #pragma unroll
    for (int i = 0; i < 4; ++i) {          // X tile 128x32
      int q = tid + 256 * i;
      int row = q >> 3;
      int kq = (q & 7) << 2;
      int gr = r0 + row;
      float4 v = make_float4(0.f, 0.f, 0.f, 0.f);
      if (gr < N_NODES) v = *(const float4*)&X[(size_t)gr * 128 + kc + kq];
      *(float4*)&As[row][kq] = v;
    }
    #pragma unroll
    for (int i = 0; i < 4; ++i) {          // W tile 32x128
      int q = tid + 256 * i;
      int kr = q >> 5;
      int nq = (q & 31) << 2;
      float4 v = *(const float4*)&W[(size_t)(kc + kr) * 128 + nq];
      *(float4*)&Bs[kr][nq] = v;
    }
    __syncthreads();
    #pragma unroll 8
    for (int k = 0; k < 32; ++k) {
      float a[8];
      #pragma unroll
      for (int i = 0; i < 8; ++i) a[i] = As[tm + 16 * i][k];
      float4 bq0 = *(const float4*)&Bs[k][tn * 8];
      float4 bq1 = *(const float4*)&Bs[k][tn * 8 + 4];
      float b[8] = {bq0.x, bq0.y, bq0.z, bq0.w, bq1.x, bq1.y, bq1.z, bq1.w};
      #pragma unroll
      for (int i = 0; i < 8; ++i)
        #pragma unroll
        for (int j = 0; j < 8; ++j)
          acc[i][j] = fmaf(a[i], b[j], acc[i][j]);
    }
    __syncthreads();
  }

  // epilogue: bf16 pack + per-head attention dots (exact fp32)
  float av_s[8], av_d[8];
  #pragma unroll
  for (int j = 0; j < 8; ++j) { av_s[j] = asrc[tn * 8 + j]; av_d[j] = adst[tn * 8 + j]; }
  int head = tn >> 2;
  #pragma unroll
  for (int i = 0; i < 8; ++i) {
    int row = r0 + tm + 16 * i;
    float ps = 0.f, pd = 0.f;
    uint us[8];
    #pragma unroll
    for (int j = 0; j < 8; ++j) {
      float v = acc[i][j];
      ps = fmaf(v, av_s[j], ps);
      pd = fmaf(v, av_d[j], pd);
      uint b = __float_as_uint(v);
      us[j] = (b + 0x7fffu + ((b >> 16) & 1u)) >> 16;   // RNE to bf16
    }
    // reduce over the 4 threads (same tm, same head): lanes base-aligned to 4
    ps += __shfl_xor(ps, 1); ps += __shfl_xor(ps, 2);
    pd += __shfl_xor(pd, 1); pd += __shfl_xor(pd, 2);
    if (row < N_NODES) {
      uint4 p;
      p.x = us[0] | (us[1] << 16);
      p.y = us[2] | (us[3] << 16);
      p.z = us[4] | (us[5] << 16);
      p.w = us[6] | (us[7] << 16);
      *(uint4*)&hbu[(size_t)row * 64 + tn * 4] = p;
      if ((tn & 3) == 0) {
        es[row * 4 + head] = ps;
        ed[row * 4 + head] = pd;
      }
    }
  }
}

// one wave per destination node. Phase A: lanes parallel over <=64 edges,
// exp-weights computed once per edge, stashed in LDS ([head*68+edge]:
// conflict-free for phase B's 16-address read), denominator per-lane float4.
// Phase B: 4 edges per vmem instruction -- 16 lanes own one edge each, lane
// reads uint4 (8 channels); 2 groups unrolled (8 edges in flight). Cross-group
// reduce + normalize in epilogue.
__global__ __launch_bounds__(256) void k_attn(const uint* __restrict__ hb,
                                              const float* __restrict__ es,
                                              const float* __restrict__ ed,
                                              const int* __restrict__ rowstart,
                                              const int* __restrict__ col,
                                              const float* __restrict__ bias,
                                              float* __restrict__ outp, int do_relu) {
  __shared__ float swv[4][4 * 68];   // [wave][head*68 + edge]
  __shared__ int   ssc[4][64];       // [wave][edge] = src<<8 (byte offset of h row)
  int lane = threadIdx.x & 63;
  int wv = threadIdx.x >> 6;
  int n = blockIdx.x * 4 + wv;
  if (n >= N_NODES) return;
  int s = rowstart[n], t = rowstart[n + 1];
  int sub = lane & 15;         // channel-group owner (8 channels)
  int esel = lane >> 4;        // edge-in-group selector (0..3)
  int head2 = sub >> 2;        // head of this lane's 8 channels
  float4 edv = *(const float4*)&ed[n * 4];
  const char* hbb = (const char*)hb + (uint)sub * 16u;   // lane's 16B slice
  const char* esb = (const char*)es;
  float* wv0 = swv[wv];
  int* sc0 = ssc[wv];

  float4 denv = make_float4(0.f, 0.f, 0.f, 0.f);
  float acc[8];
  #pragma unroll
  for (int j = 0; j < 8; ++j) acc[j] = 0.f;

  for (int base = s; base < t; base += 64) {
    int nthis = t - base; if (nthis > 64) nthis = 64;
    int npad = (nthis + 7) & ~7;
    // ---- phase A ----
    if (lane < nthis) {
      int sc = col[base + lane];
      float4 esv = *(const float4*)(esb + ((uint)sc << 4));
      float w0 = __expf(lrelu(esv.x + edv.x));
      float w1 = __expf(lrelu(esv.y + edv.y));
      float w2 = __expf(lrelu(esv.z + edv.z));
      float w3 = __expf(lrelu(esv.w + edv.w));
      denv.x += w0; denv.y += w1; denv.z += w2; denv.w += w3;
      wv0[0 * 68 + lane] = w0;
      wv0[1 * 68 + lane] = w1;
      wv0[2 * 68 + lane] = w2;
      wv0[3 * 68 + lane] = w3;
      sc0[lane] = sc << 8;
    } else if (lane < npad) {
      wv0[0 * 68 + lane] = 0.f;
      wv0[1 * 68 + lane] = 0.f;
      wv0[2 * 68 + lane] = 0.f;
      wv0[3 * 68 + lane] = 0.f;
      sc0[lane] = 0;
    }
    asm volatile("s_waitcnt lgkmcnt(0)" ::: "memory");
    // ---- phase B: 8 edges per iteration (2 groups of 4) ----
    for (int i = 0; i < npad; i += 8) {
      int e0 = i + esel, e1 = i + 4 + esel;
      float w0 = wv0[head2 * 68 + e0];
      float w1 = wv0[head2 * 68 + e1];
      int so0 = sc0[e0], so1 = sc0[e1];
      uint4 q0 = *(const uint4*)(hbb + (uint)so0);
      uint4 q1 = *(const uint4*)(hbb + (uint)so1);
      acc[0] = fmaf(w0, bf_lo(q0.x), acc[0]); acc[1] = fmaf(w0, bf_hi(q0.x), acc[1]);
      acc[2] = fmaf(w0, bf_lo(q0.y), acc[2]); acc[3] = fmaf(w0, bf_hi(q0.y), acc[3]);
      acc[4] = fmaf(w0, bf_lo(q0.z), acc[4]); acc[5] = fmaf(w0, bf_hi(q0.z), acc[5]);
      acc[6] = fmaf(w0, bf_lo(q0.w), acc[6]); acc[7] = fmaf(w0, bf_hi(q0.w), acc[7]);
      acc[0] = fmaf(w1, bf_lo(q1.x), acc[0]); acc[1] = fmaf(w1, bf_hi(q1.x), acc[1]);
      acc[2] = fmaf(w1, bf_lo(q1.y), acc[2]); acc[3] = fmaf(w1, bf_hi(q1.y), acc[3]);
      acc[4] = fmaf(w1, bf_lo(q1.z), acc[4]); acc[5] = fmaf(w1, bf_hi(q1.z), acc[5]);
      acc[6] = fmaf(w1, bf_lo(q1.w), acc[6]); acc[7] = fmaf(w1, bf_hi(q1.w), acc[7]);
    }
  }
  // reduce partial sums across the 4 edge-selector groups
  #pragma unroll
  for (int j = 0; j < 8; ++j) {
    acc[j] += __shfl_xor(acc[j], 16);
    acc[j] += __shfl_xor(acc[j], 32);
  }
  // reduce denominator across lanes (once per node)
  #pragma unroll
  for (int off = 1; off < 64; off <<= 1) {
    denv.x += __shfl_xor(denv.x, off);
    denv.y += __shfl_xor(denv.y, off);
    denv.z += __shfl_xor(denv.z, off);
    denv.w += __shfl_xor(denv.w, off);
  }
  float den = (head2 & 2) ? ((head2 & 1) ? denv.w : denv.z)
                          : ((head2 & 1) ? denv.y : denv.x);
  float inv = 1.0f / (den + 1e-16f);
  if (lane < 32) {
    int half = lane >> 4;            // 0 or 1
    int c = sub * 8 + half * 4;
    float4 bb = *(const float4*)&bias[c];
    float o0 = acc[half * 4 + 0] * inv + bb.x;
    float o1 = acc[half * 4 + 1] * inv + bb.y;
    float o2 = acc[half * 4 + 2] * inv + bb.z;
    float o3 = acc[half * 4 + 3] * inv + bb.w;
    if (do_relu) {
      o0 = fmaxf(o0, 0.f); o1 = fmaxf(o1, 0.f);
      o2 = fmaxf(o2, 0.f); o3 = fmaxf(o3, 0.f);
    }
    *(float4*)&outp[(size_t)n * 128 + c] = make_float4(o0, o1, o2, o3);
  }
}

// one block per graph: mean-pool (binary search on sorted batch) + 128->4 classifier
__global__ __launch_bounds__(128) void k_poolcls(const float* __restrict__ out2,
                                                 const int* __restrict__ batch,
                                                 const float* __restrict__ wc,
                                                 const float* __restrict__ bc,
                                                 float* __restrict__ y) {
  int b = blockIdx.x;
  int c = threadIdx.x;
  int lo = 0, hi = N_NODES;
  while (lo < hi) { int mid = (lo + hi) >> 1; if (batch[mid] < b) lo = mid + 1; else hi = mid; }
  int s = lo;
  lo = s; hi = N_NODES;
  while (lo < hi) { int mid = (lo + hi) >> 1; if (batch[mid] < b + 1) lo = mid + 1; else hi = mid; }
  int e = lo;
  float acc0 = 0.f, acc1 = 0.f, acc2 = 0.f, acc3 = 0.f;
  int nidx = s;
  for (; nidx + 4 <= e; nidx += 4) {
    acc0 += out2[(size_t)nidx * 128 + c];
    acc1 += out2[(size_t)(nidx + 1) * 128 + c];
    acc2 += out2[(size_t)(nidx + 2) * 128 + c];
    acc3 += out2[(size_t)(nidx + 3) * 128 + c];
  }
  for (; nidx < e; ++nidx) acc0 += out2[(size_t)nidx * 128 + c];
  float acc = (acc0 + acc1) + (acc2 + acc3);
  float cnt = (float)(e - s);
  float pooled = acc / fmaxf(cnt, 1.0f);
  float4 wrow = *(const float4*)&wc[c * 4];
  float wj[4] = {wrow.x, wrow.y, wrow.z, wrow.w};
  __shared__ float red[128];
  #pragma unroll
  for (int j = 0; j < 4; ++j) {
    red[c] = pooled * wj[j];
    __syncthreads();
    for (int off = 64; off > 0; off >>= 1) {
      if (c < off) red[c] += red[c + off];
      __syncthreads();
    }
    if (c == 0) y[b * 4 + j] = red[0] + bc[j];
    __syncthreads();
  }
}

extern "C" void kernel_launch(void* const* d_in, const int* in_sizes, int n_in,
                              void* d_out, int out_size, void* d_ws, size_t ws_size,
                              hipStream_t stream) {
  const float* x    = (const float*)d_in[0];
  const int*   ei   = (const int*)d_in[1];
  const int*   batch= (const int*)d_in[2];
  const float* w1   = (const float*)d_in[3];
  const float* as1  = (const float*)d_in[4];
  const float* ad1  = (const float*)d_in[5];
  const float* b1   = (const float*)d_in[6];
  const float* w2   = (const float*)d_in[7];
  const float* as2  = (const float*)d_in[8];
  const float* ad2  = (const float*)d_in[9];
  const float* b2   = (const float*)d_in[10];
  const float* wc   = (const float*)d_in[11];
  const float* bc   = (const float*)d_in[12];
  float* y = (float*)d_out;

  char* ws = (char*)d_ws;
  size_t o = 0;
  auto take = [&](size_t bytes) { void* p = ws + o; o = (o + bytes + 255) & ~(size_t)255; return p; };
  uint*  hbu      = (uint*)take((size_t)N_NODES * 64 * 4);        // bf16 h, packed 2/word
  float* obuf     = (float*)take((size_t)N_NODES * HCH * 4);      // fp32 layer outputs
  float* es       = (float*)take((size_t)N_NODES * 4 * 4);
  float* ed       = (float*)take((size_t)N_NODES * 4 * 4);
  int*   M        = (int*)take((size_t)NSB * NBUCK * 4);          // per-block bucket hist/prefix
  int*   bstart   = (int*)take((size_t)(NBUCK + 1) * 4);
  uint*  part     = (uint*)take((size_t)EPLUS * 4);               // bucket-grouped packed edges
  int*   rowstart = (int*)take((size_t)(N_NODES + 1) * 4);
  int*   col      = (int*)take((size_t)EPLUS * 4);

  const int GW = N_NODES / 4;               // 12500 wave-per-node
  const int GG = (N_NODES + 127) / 128;     // 391 gemm blocks

  // ---- CSR build (no global returning atomics) ----
  k_pA<<<NSB, 256, 0, stream>>>(ei, M);
  k_pB<<<1, 1024, 0, stream>>>(M, bstart);
  k_pC<<<NSB, 256, 0, stream>>>(ei, M, bstart, part);
  k_pD<<<NBUCK, 256, 0, stream>>>(part, bstart, rowstart, col);

  // ---- layer 1 ----
  k_gemm_fused<<<GG, 256, 0, stream>>>(x, w1, as1, ad1, hbu, es, ed);
  k_attn<<<GW, 256, 0, stream>>>(hbu, es, ed, rowstart, col, b1, obuf, 1);

  // ---- layer 2 ----
  k_gemm_fused<<<GG, 256, 0, stream>>>(obuf, w2, as2, ad2, hbu, es, ed);
  k_attn<<<GW, 256, 0, stream>>>(hbu, es, ed, rowstart, col, b2, obuf, 0);

  // ---- pool + classifier ----
  k_poolcls<<<NB, 128, 0, stream>>>(obuf, batch, wc, bc, y);
}